// Round 11
// baseline (163.031 us; speedup 1.0000x reference)
//
#include <hip/hip_runtime.h>
#include <hip/hip_bf16.h>
#include <math.h>

typedef __bf16 bf16_t;
typedef bf16_t bf16x8 __attribute__((ext_vector_type(8)));
typedef bf16_t bf16x4 __attribute__((ext_vector_type(4)));
typedef float f32x4 __attribute__((ext_vector_type(4)));
typedef float f32x16 __attribute__((ext_vector_type(16)));

#define DEV_INLINE __device__ __forceinline__

constexpr int B_ = 4, T_ = 2048, DM = 1024, NH = 8, RK = 64;
constexpr int BT = B_ * T_;        // 8192
constexpr int QC = NH * RK;        // 512
constexpr int CQW = RK + QC;       // 576: fused [c | q~] row width
// softmax scale baked into Wq_eff: (1/sqrt(256)) * log2(e)
#define QK_SCALE 0.09016844f

// ---------------------------------------------------------------- cast f32->bf16
__global__ void cast_f32_bf16(const float* __restrict__ in, bf16_t* __restrict__ out, int n) {
  int i = (blockIdx.x * blockDim.x + threadIdx.x) * 4;
  if (i >= n) return;
  const float4 v = *reinterpret_cast<const float4*>(in + i);
  bf16x4 o;
  o[0] = (bf16_t)v.x; o[1] = (bf16_t)v.y; o[2] = (bf16_t)v.z; o[3] = (bf16_t)v.w;
  *reinterpret_cast<bf16x4*>(out + i) = o;
}

// ---------------------------------------------------------------- Wq_eff[(h*64+r), m] = scale * sum_d Wk_up[(h*256+d)*64+r] * Wq[(h*256+d)*1024+m]
__global__ void build_wq_eff(const float* __restrict__ Wku, const float* __restrict__ Wq,
                             bf16_t* __restrict__ out) {
  const int m = blockIdx.x * 256 + threadIdx.x;   // [0,1024)
  const int h = blockIdx.y;                       // [0,8)
  const int r0 = blockIdx.z * 8;                  // [0,64) step 8
  float s[8] = {};
  const float* wk = Wku + (size_t)h * 256 * 64 + r0;
  const float* wq = Wq + (size_t)h * 256 * 1024 + m;
  for (int d = 0; d < 256; ++d) {
    float qv = wq[(size_t)d * 1024];
#pragma unroll
    for (int j = 0; j < 8; ++j) s[j] += wk[d * 64 + j] * qv;
  }
#pragma unroll
  for (int j = 0; j < 8; ++j)
    out[(size_t)(h * 64 + r0 + j) * 1024 + m] = (bf16_t)(s[j] * QK_SCALE);
}

// ---------------------------------------------------------------- W_eff[m*512 + h*64 + r] = sum_d Wo[m*2048 + h*256 + d] * Wv_up[(h*256+d)*64 + r]
// 8 m-rows per block: Wvu slice read once per block (64 MB total vs 512 MB).
__global__ void build_w_eff(const float* __restrict__ Wo, const float* __restrict__ Wvu,
                            bf16_t* __restrict__ out) {
  const int m0 = blockIdx.x * 8;                   // [0,1024) step 8
  const int h = blockIdx.y * 4 + (threadIdx.x >> 6);
  const int r = threadIdx.x & 63;
  float s[8] = {};
  const float* wv = Wvu + (size_t)h * 256 * 64 + r;
  const float* wo = Wo + (size_t)m0 * 2048 + h * 256;
  for (int d = 0; d < 256; ++d) {
    const float wvv = wv[d * 64];
#pragma unroll
    for (int j = 0; j < 8; ++j) s[j] += wo[(size_t)j * 2048 + d] * wvv;
  }
#pragma unroll
  for (int j = 0; j < 8; ++j)
    out[(size_t)(m0 + j) * 512 + h * 64 + r] = (bf16_t)s[j];
}

// ---------------------------------------------------------------- transpose c (cols 0..63 of CQ): cT[b][r][t] = CQ[b*T+t][r]
__global__ void transpose_c(const bf16_t* __restrict__ cq, bf16_t* __restrict__ cT) {
  __shared__ bf16_t tile[64][65];
  const int b = blockIdx.y;
  const int t0 = blockIdx.x * 64;
  const int tx = threadIdx.x & 63;
  const int ty = threadIdx.x >> 6;   // 0..3
#pragma unroll
  for (int i = 0; i < 16; ++i) {
    int t = ty * 16 + i;
    tile[t][tx] = cq[((size_t)b * T_ + t0 + t) * CQW + tx];
  }
  __syncthreads();
#pragma unroll
  for (int i = 0; i < 16; ++i) {
    int r = ty * 16 + i;
    cT[((size_t)b * RK + r) * T_ + t0 + tx] = tile[tx][r];
  }
}

// ---------------------------------------------------------------- GEMM C[M,N] = A[M,K] * B[N,K]^T (bf16 in, f32 acc)
DEV_INLINE void storeC(float* p, float v) { *p = v; }
DEV_INLINE void storeC(bf16_t* p, float v) { *p = (bf16_t)v; }

DEV_INLINE void async_load16(const void* g, void* l) {
  __builtin_amdgcn_global_load_lds((__attribute__((address_space(1))) void*)g,
                                   (__attribute__((address_space(3))) void*)l, 16, 0, 0);
}

template <typename OutT>
__global__ __launch_bounds__(256) void gemm_bt(const bf16_t* __restrict__ A,
                                               const bf16_t* __restrict__ Bm,
                                               OutT* __restrict__ C, int M, int N, int K) {
  __shared__ bf16_t lA[128 * 32];
  __shared__ bf16_t lB[128 * 32];
  const int tid = threadIdx.x;
  const int lane = tid & 63;
  const int w = tid >> 6;
  const int lo = lane & 15, hi = lane >> 4;
  const int wr = w >> 1, wc = w & 1;
  const size_t row0 = (size_t)blockIdx.x * 128;
  const size_t col0 = (size_t)blockIdx.y * 128;
  const int w64 = w * 64;
  f32x4 acc[4][4] = {};

  for (int k0 = 0; k0 < K; k0 += 32) {
    __syncthreads();
#pragma unroll
    for (int j = 0; j < 2; ++j) {
      const int chunk = j * 256 + w64 + lane;
      const int r = chunk >> 2;
      const int kk = (chunk & 3) * 8;
      const bf16_t* gA = A + (row0 + r) * K + (k0 + kk);
      async_load16(gA, &lA[(size_t)(j * 256 + w64) * 8]);
      size_t rB = col0 + r;
      if (rB >= (size_t)N) rB = N - 1;
      const bf16_t* gB = Bm + rB * K + (k0 + kk);
      async_load16(gB, &lB[(size_t)(j * 256 + w64) * 8]);
    }
    __syncthreads();
    const bf16x8* pA = reinterpret_cast<const bf16x8*>(lA);
    const bf16x8* pB = reinterpret_cast<const bf16x8*>(lB);
    bf16x8 af[4], bfr[4];
#pragma unroll
    for (int m = 0; m < 4; ++m) af[m] = pA[(wr * 64 + m * 16 + lo) * 4 + hi];
#pragma unroll
    for (int n = 0; n < 4; ++n) bfr[n] = pB[(wc * 64 + n * 16 + lo) * 4 + hi];
#pragma unroll
    for (int m = 0; m < 4; ++m)
#pragma unroll
      for (int n = 0; n < 4; ++n)
        acc[m][n] = __builtin_amdgcn_mfma_f32_16x16x32_bf16(af[m], bfr[n], acc[m][n], 0, 0, 0);
  }
#pragma unroll
  for (int m = 0; m < 4; ++m)
#pragma unroll
    for (int n = 0; n < 4; ++n)
#pragma unroll
      for (int q = 0; q < 4; ++q) {
        const size_t row = row0 + wr * 64 + m * 16 + hi * 4 + q;
        const size_t col = col0 + wc * 64 + n * 16 + lo;
        if ((int)col < N) storeC(&C[row * N + col], acc[m][n][q]);
      }
}

// ---------------------------------------------------------------- flash attention, no-max softmax + LDS-staged K/V + split-KV
// r11: VALU-diet. l computed via MFMA ones-row trick (accl = mfma(ones, P));
// LDS read offsets precomputed (krow&7 == lq&7, sub-independent chunk XOR).
// 128 q-rows/block, 4 waves; blockIdx.z = b*2 + kvh; unnormalized O + l partials.
// CQ [BT,576] = [c | q~ (pre-scaled)], cT [B][64][T]
__global__ __launch_bounds__(256) void attn_kernel(const bf16_t* __restrict__ CQ,
                                                   const bf16_t* __restrict__ CT,
                                                   bf16_t* __restrict__ Opart,
                                                   float* __restrict__ Lpart) {
  constexpr int KVT = 64;
  constexpr int NTH = (T_ / 2) / KVT;  // 16 tiles per half
  constexpr int BUFE = KVT * 64;       // 4096 elements per K (or V) buffer
  __shared__ bf16_t Kl[2][KVT][64];  // [buf][kv][d]   8KB per buf
  __shared__ bf16_t Vl[2][64][KVT];  // [buf][d][kv]   8KB per buf
  const int tid = threadIdx.x;
  const int w = tid >> 6, lane = tid & 63;
  const int lq = lane & 31;        // q column owned by this lane
  const int hi = lane >> 5;        // k-half within fragments
  const int b = blockIdx.z >> 1, kvh = blockIdx.z & 1;
  const int h = blockIdx.y;
  const int kvbase = kvh * (T_ / 2);
  const size_t qrow = (size_t)b * T_ + blockIdx.x * 128 + w * 32;
  const bf16_t* __restrict__ cq = CQ + (size_t)b * T_ * CQW;
  const bf16_t* __restrict__ ct = CT + (size_t)b * RK * T_;

  // staging geometry: round q in {0,1}; lane covers row (q*32 + w*8 + lane/8),
  // dest chunk lane&7; source chunk pre-swizzled: (lane&7) ^ (lane>>3)
  const int srow = w * 8 + (lane >> 3);        // + q*32
  const int schunk = (lane & 7) ^ (lane >> 3); // source 16B-chunk (swizzled)

  // Q fragments (B-operand): B[k][q], lane holds Q[q=lq][kc*16 + hi*8 + j]
  bf16x8 qf[4];
#pragma unroll
  for (int kc = 0; kc < 4; ++kc)
    qf[kc] = *reinterpret_cast<const bf16x8*>(
        CQ + (qrow + lq) * CQW + RK + h * RK + kc * 16 + hi * 8);

  f32x16 acc0 = {}, acc1 = {}, accl = {};  // O^T rows 0-31/32-63; accl = l via ones-MFMA

  // ones A-fragment for the l-sum MFMA
  bf16x8 onesf;
#pragma unroll
  for (int j = 0; j < 8; ++j) onesf[j] = (bf16_t)1.0f;

  // precomputed LDS element offsets (chunk XOR is sub-independent: (sub*32+lq)&7 == lq&7)
  const bf16_t* const kl = &Kl[0][0][0];
  const bf16_t* const vl = &Vl[0][0][0];
  const int xr = lq & 7;
  int kch[4], vch[2][2];
#pragma unroll
  for (int kc = 0; kc < 4; ++kc) kch[kc] = ((((kc << 1) | hi)) ^ xr) * 8;
#pragma unroll
  for (int sub = 0; sub < 2; ++sub)
#pragma unroll
    for (int kc = 0; kc < 2; ++kc)
      vch[sub][kc] = ((((sub << 2) | (kc << 1) | hi)) ^ xr) * 8;
  const int roff0 = lq * 64, roff1 = (32 + lq) * 64;   // row bases (K: kv row; V: d row)

  // ---- stage tile 0 (4 gload_lds per wave: 2 K rounds + 2 V rounds)
#pragma unroll
  for (int q = 0; q < 2; ++q) {
    async_load16(cq + (size_t)(kvbase + q * 32 + srow) * CQW + schunk * 8,
                 &Kl[0][q * 32 + w * 8][0]);
    async_load16(ct + (size_t)(q * 32 + srow) * T_ + kvbase + schunk * 8,
                 &Vl[0][q * 32 + w * 8][0]);
  }

  for (int t = 0; t < NTH; ++t) {
    const int cur = t & 1;
    const int cbo = cur * BUFE;          // current-buffer element offset
    if (t + 1 < NTH) {
      const int kvn = kvbase + (t + 1) * KVT;
#pragma unroll
      for (int q = 0; q < 2; ++q) {
        async_load16(cq + (size_t)(kvn + q * 32 + srow) * CQW + schunk * 8,
                     &Kl[cur ^ 1][q * 32 + w * 8][0]);
        async_load16(ct + (size_t)(q * 32 + srow) * T_ + kvn + schunk * 8,
                     &Vl[cur ^ 1][q * 32 + w * 8][0]);
      }
      asm volatile("s_waitcnt vmcnt(4)" ::: "memory");  // tile t's 4 loads done
    } else {
      asm volatile("s_waitcnt vmcnt(0)" ::: "memory");
    }
    __builtin_amdgcn_s_barrier();
    __builtin_amdgcn_sched_barrier(0);

#pragma unroll
    for (int sub = 0; sub < 2; ++sub) {
      // ---- K fragments from LDS (precomputed offsets)
      const int krb = cbo + (sub ? roff1 : roff0);
      bf16x8 kf[4];
#pragma unroll
      for (int kc = 0; kc < 4; ++kc)
        kf[kc] = *reinterpret_cast<const bf16x8*>(kl + krb + kch[kc]);
      // ---- S^T = K * Q^T
      f32x16 s = {};
#pragma unroll
      for (int kc = 0; kc < 4; ++kc)
        s = __builtin_amdgcn_mfma_f32_32x32x16_bf16(kf[kc], qf[kc], s, 0, 0, 0);

      // ---- P = exp2(s) directly (|s| <~ 3; no max tracking needed)
      float p[16];
#pragma unroll
      for (int i = 0; i < 16; ++i) p[i] = __builtin_amdgcn_exp2f(s[i]);

      // ---- pack P to bf16 + redistribute halves (distinct regs -> permlane safe)
      unsigned pw[8];
#pragma unroll
      for (int i = 0; i < 8; ++i)
        asm("v_cvt_pk_bf16_f32 %0, %1, %2" : "=v"(pw[i]) : "v"(p[2 * i]), "v"(p[2 * i + 1]));
      asm("v_permlane32_swap_b32 %0, %1" : "+v"(pw[0]), "+v"(pw[2]));
      asm("v_permlane32_swap_b32 %0, %1" : "+v"(pw[1]), "+v"(pw[3]));
      asm("v_permlane32_swap_b32 %0, %1" : "+v"(pw[4]), "+v"(pw[6]));
      asm("v_permlane32_swap_b32 %0, %1" : "+v"(pw[5]), "+v"(pw[7]));
      union { unsigned u[4]; bf16x8 v; } pb0, pb1;
      pb0.u[0] = pw[0]; pb0.u[1] = pw[1]; pb0.u[2] = pw[2]; pb0.u[3] = pw[3];
      pb1.u[0] = pw[4]; pb1.u[1] = pw[5]; pb1.u[2] = pw[6]; pb1.u[3] = pw[7];

      // ---- V^T fragments from LDS (precomputed offsets)
      bf16x8 vf0[2], vf1[2];
#pragma unroll
      for (int kc = 0; kc < 2; ++kc) {
        vf0[kc] = *reinterpret_cast<const bf16x8*>(vl + cbo + roff0 + vch[sub][kc]);
        vf1[kc] = *reinterpret_cast<const bf16x8*>(vl + cbo + roff1 + vch[sub][kc]);
      }

      // ---- O^T += V^T * P ; l via ones-row MFMA (replaces 15-add tree + epilogue shfl)
      acc0 = __builtin_amdgcn_mfma_f32_32x32x16_bf16(vf0[0], pb0.v, acc0, 0, 0, 0);
      acc0 = __builtin_amdgcn_mfma_f32_32x32x16_bf16(vf0[1], pb1.v, acc0, 0, 0, 0);
      acc1 = __builtin_amdgcn_mfma_f32_32x32x16_bf16(vf1[0], pb0.v, acc1, 0, 0, 0);
      acc1 = __builtin_amdgcn_mfma_f32_32x32x16_bf16(vf1[1], pb1.v, acc1, 0, 0, 0);
      accl = __builtin_amdgcn_mfma_f32_32x32x16_bf16(onesf, pb0.v, accl, 0, 0, 0);
      accl = __builtin_amdgcn_mfma_f32_32x32x16_bf16(onesf, pb1.v, accl, 0, 0, 0);
    }

    __builtin_amdgcn_sched_barrier(0);
    __builtin_amdgcn_s_barrier();   // all waves done reading buf before next stage overwrites
  }

  // ---- epilogue: l = accl[0] (every row of the ones-MFMA output equals sum P[.,q])
  const float ltot = accl[0];
  const size_t obase = (size_t)kvh * BT * QC + (qrow + lq) * QC + h * RK;
#pragma unroll
  for (int g = 0; g < 4; ++g) {
    bf16x4 o0, o1;
#pragma unroll
    for (int j = 0; j < 4; ++j) {
      o0[j] = (bf16_t)acc0[g * 4 + j];
      o1[j] = (bf16_t)acc1[g * 4 + j];
    }
    const int d0 = g * 8 + hi * 4;
    *reinterpret_cast<bf16x4*>(Opart + obase + d0) = o0;
    *reinterpret_cast<bf16x4*>(Opart + obase + 32 + d0) = o1;
  }
  if (lane < 32)
    Lpart[(((size_t)kvh * B_ + b) * NH + h) * T_ + blockIdx.x * 128 + w * 32 + lq] = ltot;
}

// ---------------------------------------------------------------- combine: U = (O1+O2)/(l1+l2)
__global__ __launch_bounds__(256) void combine_kernel(const bf16_t* __restrict__ Opart,
                                                      const float* __restrict__ Lpart,
                                                      bf16_t* __restrict__ U) {
  const int gid = blockIdx.x * 256 + threadIdx.x;   // BT*512/8 = 524288 threads
  const int row = gid >> 6;
  const int c8 = (gid & 63) * 8;
  const int h = c8 >> 6;
  const int b = row >> 11, t = row & (T_ - 1);
  const float l1 = Lpart[(((size_t)0 * B_ + b) * NH + h) * T_ + t];
  const float l2 = Lpart[(((size_t)1 * B_ + b) * NH + h) * T_ + t];
  const float inv = 1.0f / (l1 + l2);
  const bf16x8 o1 = *reinterpret_cast<const bf16x8*>(Opart + (size_t)row * QC + c8);
  const bf16x8 o2 = *reinterpret_cast<const bf16x8*>(Opart + (size_t)BT * QC + (size_t)row * QC + c8);
  bf16x8 u;
#pragma unroll
  for (int j = 0; j < 8; ++j) u[j] = (bf16_t)(((float)o1[j] + (float)o2[j]) * inv);
  *reinterpret_cast<bf16x8*>(U + (size_t)row * QC + c8) = u;
}

// ---------------------------------------------------------------- launch
extern "C" void kernel_launch(void* const* d_in, const int* in_sizes, int n_in,
                              void* d_out, int out_size, void* d_ws, size_t ws_size,
                              hipStream_t stream) {
  const float* x   = (const float*)d_in[0];
  const float* Wq  = (const float*)d_in[1];
  const float* Wkd = (const float*)d_in[2];
  const float* Wku = (const float*)d_in[3];
  const float* Wvu = (const float*)d_in[4];
  const float* Wo  = (const float*)d_in[5];
  float* out = (float*)d_out;

  char* ws = (char*)d_ws;
  bf16_t* xb    = (bf16_t*)(ws + 0);          // 8192*1024 bf16 = 16 MiB
  bf16_t* CQb   = (bf16_t*)(ws + 16777216);   // 8192*576         9 MiB
  bf16_t* Ub    = (bf16_t*)(ws + 26214400);   // 8192*512         8 MiB
  bf16_t* Wcat  = (bf16_t*)(ws + 34603008);   // 576*1024         1.125 MiB
  bf16_t* Wfe   = (bf16_t*)(ws + 35782656);   // 1024*512         1 MiB
  bf16_t* cTb   = (bf16_t*)(ws + 36831232);   // 4*64*2048        1 MiB
  bf16_t* Opart = (bf16_t*)(ws + 37879808);   // 2*8192*512 bf16  16 MiB
  float*  Lpart = (float*)(ws + 54657024);    // 2*4*8*2048 f32   0.5 MiB

  // Wcat rows 0..63 = Wkv_down (bf16, unscaled); rows 64..575 = Wq_eff (pre-scaled)
  cast_f32_bf16<<<8192, 256, 0, stream>>>(x, xb, BT * DM);
  cast_f32_bf16<<<64, 256, 0, stream>>>(Wkd, Wcat, RK * DM);
  build_wq_eff<<<dim3(4, 8, 8), 256, 0, stream>>>(Wku, Wq, Wcat + (size_t)RK * DM);
  build_w_eff<<<dim3(128, 2), 256, 0, stream>>>(Wo, Wvu, Wfe);

  // [c | q~] = x @ Wcat^T   [8192, 576]
  gemm_bt<bf16_t><<<dim3(BT / 128, 5), 256, 0, stream>>>(xb, Wcat, CQb, BT, CQW, DM);
  // cT from CQ cols 0..63
  transpose_c<<<dim3(T_ / 64, B_), 256, 0, stream>>>(CQb, cTb);
  // attention partials (split-KV) -> Opart/Lpart
  attn_kernel<<<dim3(T_ / 128, NH, B_ * 2), 256, 0, stream>>>(CQb, cTb, Opart, Lpart);
  // combine -> U [8192, 512]
  combine_kernel<<<BT * QC / 8 / 256, 256, 0, stream>>>(Opart, Lpart, Ub);
  // out = U @ W_eff^T    [8192, 1024] f32
  gemm_bt<float><<<dim3(BT / 128, DM / 128), 256, 0, stream>>>(Ub, Wfe, out, BT, DM, QC);
}

// Round 13
// 148.076 us; speedup vs baseline: 1.1010x; 1.1010x over previous
//
#include <hip/hip_runtime.h>
#include <hip/hip_bf16.h>
#include <math.h>

typedef __bf16 bf16_t;
typedef bf16_t bf16x8 __attribute__((ext_vector_type(8)));
typedef bf16_t bf16x4 __attribute__((ext_vector_type(4)));
typedef float f32x4 __attribute__((ext_vector_type(4)));
typedef float f32x16 __attribute__((ext_vector_type(16)));

#define DEV_INLINE __device__ __forceinline__

constexpr int B_ = 4, T_ = 2048, DM = 1024, NH = 8, RK = 64;
constexpr int BT = B_ * T_;        // 8192
constexpr int QC = NH * RK;        // 512
constexpr int CQW = RK + QC;       // 576: fused [c | q~] row width
// softmax scale baked into Wq_eff: (1/sqrt(256)) * log2(e)
#define QK_SCALE 0.09016844f

// ---------------------------------------------------------------- cast f32->bf16
__global__ void cast_f32_bf16(const float* __restrict__ in, bf16_t* __restrict__ out, int n) {
  int i = (blockIdx.x * blockDim.x + threadIdx.x) * 4;
  if (i >= n) return;
  const float4 v = *reinterpret_cast<const float4*>(in + i);
  bf16x4 o;
  o[0] = (bf16_t)v.x; o[1] = (bf16_t)v.y; o[2] = (bf16_t)v.z; o[3] = (bf16_t)v.w;
  *reinterpret_cast<bf16x4*>(out + i) = o;
}

// ---------------------------------------------------------------- Wq_eff[(h*64+r), m] = scale * sum_d Wk_up[(h*256+d)*64+r] * Wq[(h*256+d)*1024+m]
__global__ void build_wq_eff(const float* __restrict__ Wku, const float* __restrict__ Wq,
                             bf16_t* __restrict__ out) {
  const int m = blockIdx.x * 256 + threadIdx.x;   // [0,1024)
  const int h = blockIdx.y;                       // [0,8)
  const int r0 = blockIdx.z * 4;                  // [0,64) step 4
  float s[4] = {};
  const float* wk = Wku + (size_t)h * 256 * 64 + r0;
  const float* wq = Wq + (size_t)h * 256 * 1024 + m;
  for (int d = 0; d < 256; ++d) {
    float qv = wq[(size_t)d * 1024];
#pragma unroll
    for (int j = 0; j < 4; ++j) s[j] += wk[d * 64 + j] * qv;
  }
#pragma unroll
  for (int j = 0; j < 4; ++j)
    out[(size_t)(h * 64 + r0 + j) * 1024 + m] = (bf16_t)(s[j] * QK_SCALE);
}

// ---------------------------------------------------------------- W_eff[m*512 + h*64 + r] = sum_d Wo[m*2048 + h*256 + d] * Wv_up[(h*256+d)*64 + r]
__global__ void build_w_eff(const float* __restrict__ Wo, const float* __restrict__ Wvu,
                            bf16_t* __restrict__ out) {
  const int m0 = blockIdx.x * 4;                   // [0,1024) step 4
  const int h = blockIdx.y * 4 + (threadIdx.x >> 6);
  const int r = threadIdx.x & 63;
  float s[4] = {};
  const float* wv = Wvu + (size_t)h * 256 * 64 + r;
  const float* wo = Wo + (size_t)m0 * 2048 + h * 256;
  for (int d = 0; d < 256; ++d) {
    const float wvv = wv[d * 64];
#pragma unroll
    for (int j = 0; j < 4; ++j) s[j] += wo[(size_t)j * 2048 + d] * wvv;
  }
#pragma unroll
  for (int j = 0; j < 4; ++j)
    out[(size_t)(m0 + j) * 512 + h * 64 + r] = (bf16_t)s[j];
}

// ---------------------------------------------------------------- transpose c (cols 0..63 of CQ): cT[b][r][t] = CQ[b*T+t][r]
__global__ void transpose_c(const bf16_t* __restrict__ cq, bf16_t* __restrict__ cT) {
  __shared__ bf16_t tile[64][65];
  const int b = blockIdx.y;
  const int t0 = blockIdx.x * 64;
  const int tx = threadIdx.x & 63;
  const int ty = threadIdx.x >> 6;   // 0..3
#pragma unroll
  for (int i = 0; i < 16; ++i) {
    int t = ty * 16 + i;
    tile[t][tx] = cq[((size_t)b * T_ + t0 + t) * CQW + tx];
  }
  __syncthreads();
#pragma unroll
  for (int i = 0; i < 16; ++i) {
    int r = ty * 16 + i;
    cT[((size_t)b * RK + r) * T_ + t0 + tx] = tile[tx][r];
  }
}

// ---------------------------------------------------------------- GEMM C[M,N] = A[M,K] * B[N,K]^T (bf16 in, f32 acc)
DEV_INLINE void storeC(float* p, float v) { *p = v; }
DEV_INLINE void storeC(bf16_t* p, float v) { *p = (bf16_t)v; }

DEV_INLINE void async_load16(const void* g, void* l) {
  __builtin_amdgcn_global_load_lds((__attribute__((address_space(1))) void*)g,
                                   (__attribute__((address_space(3))) void*)l, 16, 0, 0);
}

template <typename OutT>
__global__ __launch_bounds__(256) void gemm_bt(const bf16_t* __restrict__ A,
                                               const bf16_t* __restrict__ Bm,
                                               OutT* __restrict__ C, int M, int N, int K) {
  __shared__ bf16_t lA[128 * 32];
  __shared__ bf16_t lB[128 * 32];
  const int tid = threadIdx.x;
  const int lane = tid & 63;
  const int w = tid >> 6;
  const int lo = lane & 15, hi = lane >> 4;
  const int wr = w >> 1, wc = w & 1;
  const size_t row0 = (size_t)blockIdx.x * 128;
  const size_t col0 = (size_t)blockIdx.y * 128;
  const int w64 = w * 64;
  f32x4 acc[4][4] = {};

  for (int k0 = 0; k0 < K; k0 += 32) {
    __syncthreads();
#pragma unroll
    for (int j = 0; j < 2; ++j) {
      const int chunk = j * 256 + w64 + lane;
      const int r = chunk >> 2;
      const int kk = (chunk & 3) * 8;
      const bf16_t* gA = A + (row0 + r) * K + (k0 + kk);
      async_load16(gA, &lA[(size_t)(j * 256 + w64) * 8]);
      size_t rB = col0 + r;
      if (rB >= (size_t)N) rB = N - 1;
      const bf16_t* gB = Bm + rB * K + (k0 + kk);
      async_load16(gB, &lB[(size_t)(j * 256 + w64) * 8]);
    }
    __syncthreads();
    const bf16x8* pA = reinterpret_cast<const bf16x8*>(lA);
    const bf16x8* pB = reinterpret_cast<const bf16x8*>(lB);
    bf16x8 af[4], bfr[4];
#pragma unroll
    for (int m = 0; m < 4; ++m) af[m] = pA[(wr * 64 + m * 16 + lo) * 4 + hi];
#pragma unroll
    for (int n = 0; n < 4; ++n) bfr[n] = pB[(wc * 64 + n * 16 + lo) * 4 + hi];
#pragma unroll
    for (int m = 0; m < 4; ++m)
#pragma unroll
      for (int n = 0; n < 4; ++n)
        acc[m][n] = __builtin_amdgcn_mfma_f32_16x16x32_bf16(af[m], bfr[n], acc[m][n], 0, 0, 0);
  }
#pragma unroll
  for (int m = 0; m < 4; ++m)
#pragma unroll
    for (int n = 0; n < 4; ++n)
#pragma unroll
      for (int q = 0; q < 4; ++q) {
        const size_t row = row0 + wr * 64 + m * 16 + hi * 4 + q;
        const size_t col = col0 + wc * 64 + n * 16 + lo;
        if ((int)col < N) storeC(&C[row * N + col], acc[m][n][q]);
      }
}

// ---------------------------------------------------------------- flash attention, no-max softmax + LDS-staged K/V
// r13: EXACT r11 loop structure (KVT=64, proven 3 rounds), full KV per block
// (kvbase=0), normalized direct U output (no split-KV/combine).
// 128 q-rows/block, 4 waves; grid 512. l via ones-row MFMA; precomputed offsets.
// CQ [BT,576] = [c | q~ (pre-scaled)], cT [B][64][T], U [BT,512]
__global__ __launch_bounds__(256) void attn_kernel(const bf16_t* __restrict__ CQ,
                                                   const bf16_t* __restrict__ CT,
                                                   bf16_t* __restrict__ U) {
  constexpr int KVT = 64;
  constexpr int NT = T_ / KVT;         // 32 tiles
  constexpr int BUFE = KVT * 64;       // 4096 elements per K (or V) buffer
  __shared__ bf16_t Kl[2][KVT][64];  // [buf][kv][d]   8KB per buf
  __shared__ bf16_t Vl[2][64][KVT];  // [buf][d][kv]   8KB per buf
  const int tid = threadIdx.x;
  const int w = tid >> 6, lane = tid & 63;
  const int lq = lane & 31;        // q column owned by this lane
  const int hi = lane >> 5;        // k-half within fragments
  const int b = blockIdx.z;
  const int h = blockIdx.y;
  const size_t qrow = (size_t)b * T_ + blockIdx.x * 128 + w * 32;
  const bf16_t* __restrict__ cq = CQ + (size_t)b * T_ * CQW;
  const bf16_t* __restrict__ ct = CT + (size_t)b * RK * T_;

  // staging geometry: round q in {0,1}; lane covers row (q*32 + w*8 + lane/8),
  // dest chunk lane&7; source chunk pre-swizzled: (lane&7) ^ (lane>>3)
  const int srow = w * 8 + (lane >> 3);        // + q*32
  const int schunk = (lane & 7) ^ (lane >> 3); // source 16B-chunk (swizzled)

  // Q fragments (B-operand): B[k][q], lane holds Q[q=lq][kc*16 + hi*8 + j]
  bf16x8 qf[4];
#pragma unroll
  for (int kc = 0; kc < 4; ++kc)
    qf[kc] = *reinterpret_cast<const bf16x8*>(
        CQ + (qrow + lq) * CQW + RK + h * RK + kc * 16 + hi * 8);

  f32x16 acc0 = {}, acc1 = {}, accl = {};  // O^T rows 0-31/32-63; accl = l via ones-MFMA

  // ones A-fragment for the l-sum MFMA
  bf16x8 onesf;
#pragma unroll
  for (int j = 0; j < 8; ++j) onesf[j] = (bf16_t)1.0f;

  // precomputed LDS element offsets (chunk XOR is sub-independent: (sub*32+lq)&7 == lq&7)
  const bf16_t* const kl = &Kl[0][0][0];
  const bf16_t* const vl = &Vl[0][0][0];
  const int xr = lq & 7;
  int kch[4], vch[2][2];
#pragma unroll
  for (int kc = 0; kc < 4; ++kc) kch[kc] = ((((kc << 1) | hi)) ^ xr) * 8;
#pragma unroll
  for (int sub = 0; sub < 2; ++sub)
#pragma unroll
    for (int kc = 0; kc < 2; ++kc)
      vch[sub][kc] = ((((sub << 2) | (kc << 1) | hi)) ^ xr) * 8;
  const int roff0 = lq * 64, roff1 = (32 + lq) * 64;   // row bases (K: kv row; V: d row)

  // ---- stage tile 0 (4 gload_lds per wave: 2 K rounds + 2 V rounds)
#pragma unroll
  for (int q = 0; q < 2; ++q) {
    async_load16(cq + (size_t)(q * 32 + srow) * CQW + schunk * 8,
                 &Kl[0][q * 32 + w * 8][0]);
    async_load16(ct + (size_t)(q * 32 + srow) * T_ + schunk * 8,
                 &Vl[0][q * 32 + w * 8][0]);
  }

  for (int t = 0; t < NT; ++t) {
    const int cur = t & 1;
    const int cbo = cur * BUFE;          // current-buffer element offset
    if (t + 1 < NT) {
      const int kvn = (t + 1) * KVT;
#pragma unroll
      for (int q = 0; q < 2; ++q) {
        async_load16(cq + (size_t)(kvn + q * 32 + srow) * CQW + schunk * 8,
                     &Kl[cur ^ 1][q * 32 + w * 8][0]);
        async_load16(ct + (size_t)(q * 32 + srow) * T_ + kvn + schunk * 8,
                     &Vl[cur ^ 1][q * 32 + w * 8][0]);
      }
      asm volatile("s_waitcnt vmcnt(4)" ::: "memory");  // tile t's 4 loads done
    } else {
      asm volatile("s_waitcnt vmcnt(0)" ::: "memory");
    }
    __builtin_amdgcn_s_barrier();
    __builtin_amdgcn_sched_barrier(0);

#pragma unroll
    for (int sub = 0; sub < 2; ++sub) {
      // ---- K fragments from LDS (precomputed offsets)
      const int krb = cbo + (sub ? roff1 : roff0);
      bf16x8 kf[4];
#pragma unroll
      for (int kc = 0; kc < 4; ++kc)
        kf[kc] = *reinterpret_cast<const bf16x8*>(kl + krb + kch[kc]);
      // ---- S^T = K * Q^T
      f32x16 s = {};
#pragma unroll
      for (int kc = 0; kc < 4; ++kc)
        s = __builtin_amdgcn_mfma_f32_32x32x16_bf16(kf[kc], qf[kc], s, 0, 0, 0);

      // ---- P = exp2(s) directly (|s| <~ 3; no max tracking needed)
      float p[16];
#pragma unroll
      for (int i = 0; i < 16; ++i) p[i] = __builtin_amdgcn_exp2f(s[i]);

      // ---- pack P to bf16 + redistribute halves (distinct regs -> permlane safe)
      unsigned pw[8];
#pragma unroll
      for (int i = 0; i < 8; ++i)
        asm("v_cvt_pk_bf16_f32 %0, %1, %2" : "=v"(pw[i]) : "v"(p[2 * i]), "v"(p[2 * i + 1]));
      asm("v_permlane32_swap_b32 %0, %1" : "+v"(pw[0]), "+v"(pw[2]));
      asm("v_permlane32_swap_b32 %0, %1" : "+v"(pw[1]), "+v"(pw[3]));
      asm("v_permlane32_swap_b32 %0, %1" : "+v"(pw[4]), "+v"(pw[6]));
      asm("v_permlane32_swap_b32 %0, %1" : "+v"(pw[5]), "+v"(pw[7]));
      union { unsigned u[4]; bf16x8 v; } pb0, pb1;
      pb0.u[0] = pw[0]; pb0.u[1] = pw[1]; pb0.u[2] = pw[2]; pb0.u[3] = pw[3];
      pb1.u[0] = pw[4]; pb1.u[1] = pw[5]; pb1.u[2] = pw[6]; pb1.u[3] = pw[7];

      // ---- V^T fragments from LDS (precomputed offsets)
      bf16x8 vf0[2], vf1[2];
#pragma unroll
      for (int kc = 0; kc < 2; ++kc) {
        vf0[kc] = *reinterpret_cast<const bf16x8*>(vl + cbo + roff0 + vch[sub][kc]);
        vf1[kc] = *reinterpret_cast<const bf16x8*>(vl + cbo + roff1 + vch[sub][kc]);
      }

      // ---- O^T += V^T * P ; l via ones-row MFMA
      acc0 = __builtin_amdgcn_mfma_f32_32x32x16_bf16(vf0[0], pb0.v, acc0, 0, 0, 0);
      acc0 = __builtin_amdgcn_mfma_f32_32x32x16_bf16(vf0[1], pb1.v, acc0, 0, 0, 0);
      acc1 = __builtin_amdgcn_mfma_f32_32x32x16_bf16(vf1[0], pb0.v, acc1, 0, 0, 0);
      acc1 = __builtin_amdgcn_mfma_f32_32x32x16_bf16(vf1[1], pb1.v, acc1, 0, 0, 0);
      accl = __builtin_amdgcn_mfma_f32_32x32x16_bf16(onesf, pb0.v, accl, 0, 0, 0);
      accl = __builtin_amdgcn_mfma_f32_32x32x16_bf16(onesf, pb1.v, accl, 0, 0, 0);
    }

    __builtin_amdgcn_sched_barrier(0);
    __builtin_amdgcn_s_barrier();   // all waves done reading buf before next stage overwrites
  }

  // ---- epilogue: l = accl[0]; normalize and store U
  const float inv = 1.0f / accl[0];
  const size_t ubase = (qrow + lq) * QC + h * RK;
#pragma unroll
  for (int g = 0; g < 4; ++g) {
    bf16x4 o0, o1;
#pragma unroll
    for (int j = 0; j < 4; ++j) {
      o0[j] = (bf16_t)(acc0[g * 4 + j] * inv);
      o1[j] = (bf16_t)(acc1[g * 4 + j] * inv);
    }
    const int d0 = g * 8 + hi * 4;
    *reinterpret_cast<bf16x4*>(U + ubase + d0) = o0;
    *reinterpret_cast<bf16x4*>(U + ubase + 32 + d0) = o1;
  }
}

// ---------------------------------------------------------------- launch
extern "C" void kernel_launch(void* const* d_in, const int* in_sizes, int n_in,
                              void* d_out, int out_size, void* d_ws, size_t ws_size,
                              hipStream_t stream) {
  const float* x   = (const float*)d_in[0];
  const float* Wq  = (const float*)d_in[1];
  const float* Wkd = (const float*)d_in[2];
  const float* Wku = (const float*)d_in[3];
  const float* Wvu = (const float*)d_in[4];
  const float* Wo  = (const float*)d_in[5];
  float* out = (float*)d_out;

  char* ws = (char*)d_ws;
  bf16_t* xb    = (bf16_t*)(ws + 0);          // 8192*1024 bf16 = 16 MiB
  bf16_t* CQb   = (bf16_t*)(ws + 16777216);   // 8192*576         9 MiB
  bf16_t* Ub    = (bf16_t*)(ws + 26214400);   // 8192*512         8 MiB
  bf16_t* Wcat  = (bf16_t*)(ws + 34603008);   // 576*1024         1.125 MiB
  bf16_t* Wfe   = (bf16_t*)(ws + 35782656);   // 1024*512         1 MiB
  bf16_t* cTb   = (bf16_t*)(ws + 36831232);   // 4*64*2048        1 MiB

  // Wcat rows 0..63 = Wkv_down (bf16, unscaled); rows 64..575 = Wq_eff (pre-scaled)
  cast_f32_bf16<<<8192, 256, 0, stream>>>(x, xb, BT * DM);
  cast_f32_bf16<<<64, 256, 0, stream>>>(Wkd, Wcat, RK * DM);
  build_wq_eff<<<dim3(4, 8, 16), 256, 0, stream>>>(Wku, Wq, Wcat + (size_t)RK * DM);
  build_w_eff<<<dim3(256, 2), 256, 0, stream>>>(Wo, Wvu, Wfe);

  // [c | q~] = x @ Wcat^T   [8192, 576]
  gemm_bt<bf16_t><<<dim3(BT / 128, 5), 256, 0, stream>>>(xb, Wcat, CQb, BT, CQW, DM);
  // cT from CQ cols 0..63
  transpose_c<<<dim3(T_ / 64, B_), 256, 0, stream>>>(CQb, cTb);
  // attention -> U [8192, 512]
  attn_kernel<<<dim3(T_ / 128, NH, B_), 256, 0, stream>>>(CQb, cTb, Ub);
  // out = U @ W_eff^T    [8192, 1024] f32
  gemm_bt<float><<<dim3(BT / 128, DM / 128), 256, 0, stream>>>(Ub, Wfe, out, BT, DM, QC);
}

// Round 16
// 145.854 us; speedup vs baseline: 1.1178x; 1.0152x over previous
//
#include <hip/hip_runtime.h>
#include <hip/hip_bf16.h>
#include <math.h>

typedef __bf16 bf16_t;
typedef bf16_t bf16x8 __attribute__((ext_vector_type(8)));
typedef bf16_t bf16x4 __attribute__((ext_vector_type(4)));
typedef float f32x4 __attribute__((ext_vector_type(4)));
typedef float f32x16 __attribute__((ext_vector_type(16)));

#define DEV_INLINE __device__ __forceinline__

constexpr int B_ = 4, T_ = 2048, DM = 1024, NH = 8, RK = 64;
constexpr int BT = B_ * T_;        // 8192
constexpr int QC = NH * RK;        // 512
constexpr int CQW = RK + QC;       // 576: fused [c | q~] row width
// softmax scale baked into Wq_eff: (1/sqrt(256)) * log2(e)
#define QK_SCALE 0.09016844f

// ---------------------------------------------------------------- cast f32->bf16
__global__ void cast_f32_bf16(const float* __restrict__ in, bf16_t* __restrict__ out, int n) {
  int i = (blockIdx.x * blockDim.x + threadIdx.x) * 4;
  if (i >= n) return;
  const float4 v = *reinterpret_cast<const float4*>(in + i);
  bf16x4 o;
  o[0] = (bf16_t)v.x; o[1] = (bf16_t)v.y; o[2] = (bf16_t)v.z; o[3] = (bf16_t)v.w;
  *reinterpret_cast<bf16x4*>(out + i) = o;
}

// ---------------------------------------------------------------- Wq_eff[(h*64+r), m] = scale * sum_d Wk_up[(h*256+d)*64+r] * Wq[(h*256+d)*1024+m]
__global__ void build_wq_eff(const float* __restrict__ Wku, const float* __restrict__ Wq,
                             bf16_t* __restrict__ out) {
  const int m = blockIdx.x * 256 + threadIdx.x;   // [0,1024)
  const int h = blockIdx.y;                       // [0,8)
  const int r0 = blockIdx.z * 4;                  // [0,64) step 4
  float s[4] = {};
  const float* wk = Wku + (size_t)h * 256 * 64 + r0;
  const float* wq = Wq + (size_t)h * 256 * 1024 + m;
  for (int d = 0; d < 256; ++d) {
    float qv = wq[(size_t)d * 1024];
#pragma unroll
    for (int j = 0; j < 4; ++j) s[j] += wk[d * 64 + j] * qv;
  }
#pragma unroll
  for (int j = 0; j < 4; ++j)
    out[(size_t)(h * 64 + r0 + j) * 1024 + m] = (bf16_t)(s[j] * QK_SCALE);
}

// ---------------------------------------------------------------- W_eff[m*512 + h*64 + r] = sum_d Wo[m*2048 + h*256 + d] * Wv_up[(h*256+d)*64 + r]
__global__ void build_w_eff(const float* __restrict__ Wo, const float* __restrict__ Wvu,
                            bf16_t* __restrict__ out) {
  const int m0 = blockIdx.x * 4;                   // [0,1024) step 4
  const int h = blockIdx.y * 4 + (threadIdx.x >> 6);
  const int r = threadIdx.x & 63;
  float s[4] = {};
  const float* wv = Wvu + (size_t)h * 256 * 64 + r;
  const float* wo = Wo + (size_t)m0 * 2048 + h * 256;
  for (int d = 0; d < 256; ++d) {
    const float wvv = wv[d * 64];
#pragma unroll
    for (int j = 0; j < 4; ++j) s[j] += wo[(size_t)j * 2048 + d] * wvv;
  }
#pragma unroll
  for (int j = 0; j < 4; ++j)
    out[(size_t)(m0 + j) * 512 + h * 64 + r] = (bf16_t)s[j];
}

// ---------------------------------------------------------------- GEMM C[M,N] = A[M,K] * B[N,K]^T (bf16 in, f32 acc)
// WRITE_CT: blocks with blockIdx.y==0 / wc==0 own output cols 0..63 (= c);
// they additionally emit the transposed copy cT[b][r][t] (replaces transpose_c).
DEV_INLINE void storeC(float* p, float v) { *p = v; }
DEV_INLINE void storeC(bf16_t* p, float v) { *p = (bf16_t)v; }

DEV_INLINE void async_load16(const void* g, void* l) {
  __builtin_amdgcn_global_load_lds((__attribute__((address_space(1))) void*)g,
                                   (__attribute__((address_space(3))) void*)l, 16, 0, 0);
}

template <typename OutT, bool WRITE_CT>
__global__ __launch_bounds__(256) void gemm_bt(const bf16_t* __restrict__ A,
                                               const bf16_t* __restrict__ Bm,
                                               OutT* __restrict__ C,
                                               bf16_t* __restrict__ CT,
                                               int M, int N, int K) {
  __shared__ bf16_t lA[128 * 32];
  __shared__ bf16_t lB[128 * 32];
  const int tid = threadIdx.x;
  const int lane = tid & 63;
  const int w = tid >> 6;
  const int lo = lane & 15, hi = lane >> 4;
  const int wr = w >> 1, wc = w & 1;
  const size_t row0 = (size_t)blockIdx.x * 128;
  const size_t col0 = (size_t)blockIdx.y * 128;
  const int w64 = w * 64;
  f32x4 acc[4][4] = {};

  for (int k0 = 0; k0 < K; k0 += 32) {
    __syncthreads();
#pragma unroll
    for (int j = 0; j < 2; ++j) {
      const int chunk = j * 256 + w64 + lane;
      const int r = chunk >> 2;
      const int kk = (chunk & 3) * 8;
      const bf16_t* gA = A + (row0 + r) * K + (k0 + kk);
      async_load16(gA, &lA[(size_t)(j * 256 + w64) * 8]);
      size_t rB = col0 + r;
      if (rB >= (size_t)N) rB = N - 1;
      const bf16_t* gB = Bm + rB * K + (k0 + kk);
      async_load16(gB, &lB[(size_t)(j * 256 + w64) * 8]);
    }
    __syncthreads();
    const bf16x8* pA = reinterpret_cast<const bf16x8*>(lA);
    const bf16x8* pB = reinterpret_cast<const bf16x8*>(lB);
    bf16x8 af[4], bfr[4];
#pragma unroll
    for (int m = 0; m < 4; ++m) af[m] = pA[(wr * 64 + m * 16 + lo) * 4 + hi];
#pragma unroll
    for (int n = 0; n < 4; ++n) bfr[n] = pB[(wc * 64 + n * 16 + lo) * 4 + hi];
#pragma unroll
    for (int m = 0; m < 4; ++m)
#pragma unroll
      for (int n = 0; n < 4; ++n)
        acc[m][n] = __builtin_amdgcn_mfma_f32_16x16x32_bf16(af[m], bfr[n], acc[m][n], 0, 0, 0);
  }
#pragma unroll
  for (int m = 0; m < 4; ++m)
#pragma unroll
    for (int n = 0; n < 4; ++n)
#pragma unroll
      for (int q = 0; q < 4; ++q) {
        const size_t row = row0 + wr * 64 + m * 16 + hi * 4 + q;
        const size_t col = col0 + wc * 64 + n * 16 + lo;
        if ((int)col < N) storeC(&C[row * N + col], acc[m][n][q]);
      }
  if (WRITE_CT && blockIdx.y == 0 && wc == 0) {
    // cols 0..63 are c; emit cT[b][r][t] (packed 4 consecutive t per store)
#pragma unroll
    for (int m = 0; m < 4; ++m)
#pragma unroll
      for (int n = 0; n < 4; ++n) {
        bf16x4 o;
#pragma unroll
        for (int q = 0; q < 4; ++q) o[q] = (bf16_t)acc[m][n][q];
        const size_t row = row0 + wr * 64 + m * 16 + hi * 4;   // + q
        const int bb = (int)(row >> 11);            // row / T_
        const int t0 = (int)(row & (T_ - 1));
        const int r = n * 16 + lo;                  // 0..63
        *reinterpret_cast<bf16x4*>(CT + ((size_t)bb * RK + r) * T_ + t0) = o;
      }
  }
}

// ---------------------------------------------------------------- flash attention, no-max softmax + LDS-staged K/V
// r16: EXACT r13 structure (proven) + s_setprio around MFMA clusters (T5).
// 128 q-rows/block, 4 waves; grid 512. l via ones-row MFMA; precomputed offsets.
// CQ [BT,576] = [c | q~ (pre-scaled)], cT [B][64][T], U [BT,512]
__global__ __launch_bounds__(256) void attn_kernel(const bf16_t* __restrict__ CQ,
                                                   const bf16_t* __restrict__ CT,
                                                   bf16_t* __restrict__ U) {
  constexpr int KVT = 64;
  constexpr int NT = T_ / KVT;         // 32 tiles
  constexpr int BUFE = KVT * 64;       // 4096 elements per K (or V) buffer
  __shared__ bf16_t Kl[2][KVT][64];  // [buf][kv][d]   8KB per buf
  __shared__ bf16_t Vl[2][64][KVT];  // [buf][d][kv]   8KB per buf
  const int tid = threadIdx.x;
  const int w = tid >> 6, lane = tid & 63;
  const int lq = lane & 31;        // q column owned by this lane
  const int hi = lane >> 5;        // k-half within fragments
  const int b = blockIdx.z;
  const int h = blockIdx.y;
  const size_t qrow = (size_t)b * T_ + blockIdx.x * 128 + w * 32;
  const bf16_t* __restrict__ cq = CQ + (size_t)b * T_ * CQW;
  const bf16_t* __restrict__ ct = CT + (size_t)b * RK * T_;

  // staging geometry: round q in {0,1}; lane covers row (q*32 + w*8 + lane/8),
  // dest chunk lane&7; source chunk pre-swizzled: (lane&7) ^ (lane>>3)
  const int srow = w * 8 + (lane >> 3);        // + q*32
  const int schunk = (lane & 7) ^ (lane >> 3); // source 16B-chunk (swizzled)

  // Q fragments (B-operand): B[k][q], lane holds Q[q=lq][kc*16 + hi*8 + j]
  bf16x8 qf[4];
#pragma unroll
  for (int kc = 0; kc < 4; ++kc)
    qf[kc] = *reinterpret_cast<const bf16x8*>(
        CQ + (qrow + lq) * CQW + RK + h * RK + kc * 16 + hi * 8);

  f32x16 acc0 = {}, acc1 = {}, accl = {};  // O^T rows 0-31/32-63; accl = l via ones-MFMA

  // ones A-fragment for the l-sum MFMA
  bf16x8 onesf;
#pragma unroll
  for (int j = 0; j < 8; ++j) onesf[j] = (bf16_t)1.0f;

  // precomputed LDS element offsets (chunk XOR is sub-independent: (sub*32+lq)&7 == lq&7)
  const bf16_t* const kl = &Kl[0][0][0];
  const bf16_t* const vl = &Vl[0][0][0];
  const int xr = lq & 7;
  int kch[4], vch[2][2];
#pragma unroll
  for (int kc = 0; kc < 4; ++kc) kch[kc] = ((((kc << 1) | hi)) ^ xr) * 8;
#pragma unroll
  for (int sub = 0; sub < 2; ++sub)
#pragma unroll
    for (int kc = 0; kc < 2; ++kc)
      vch[sub][kc] = ((((sub << 2) | (kc << 1) | hi)) ^ xr) * 8;
  const int roff0 = lq * 64, roff1 = (32 + lq) * 64;   // row bases (K: kv row; V: d row)

  // ---- stage tile 0 (4 gload_lds per wave: 2 K rounds + 2 V rounds)
#pragma unroll
  for (int q = 0; q < 2; ++q) {
    async_load16(cq + (size_t)(q * 32 + srow) * CQW + schunk * 8,
                 &Kl[0][q * 32 + w * 8][0]);
    async_load16(ct + (size_t)(q * 32 + srow) * T_ + schunk * 8,
                 &Vl[0][q * 32 + w * 8][0]);
  }

  for (int t = 0; t < NT; ++t) {
    const int cur = t & 1;
    const int cbo = cur * BUFE;          // current-buffer element offset
    if (t + 1 < NT) {
      const int kvn = (t + 1) * KVT;
#pragma unroll
      for (int q = 0; q < 2; ++q) {
        async_load16(cq + (size_t)(kvn + q * 32 + srow) * CQW + schunk * 8,
                     &Kl[cur ^ 1][q * 32 + w * 8][0]);
        async_load16(ct + (size_t)(q * 32 + srow) * T_ + kvn + schunk * 8,
                     &Vl[cur ^ 1][q * 32 + w * 8][0]);
      }
      asm volatile("s_waitcnt vmcnt(4)" ::: "memory");  // tile t's 4 loads done
    } else {
      asm volatile("s_waitcnt vmcnt(0)" ::: "memory");
    }
    __builtin_amdgcn_s_barrier();
    __builtin_amdgcn_sched_barrier(0);

#pragma unroll
    for (int sub = 0; sub < 2; ++sub) {
      // ---- K fragments from LDS (precomputed offsets)
      const int krb = cbo + (sub ? roff1 : roff0);
      bf16x8 kf[4];
#pragma unroll
      for (int kc = 0; kc < 4; ++kc)
        kf[kc] = *reinterpret_cast<const bf16x8*>(kl + krb + kch[kc]);
      // ---- S^T = K * Q^T
      f32x16 s = {};
      __builtin_amdgcn_s_setprio(1);
#pragma unroll
      for (int kc = 0; kc < 4; ++kc)
        s = __builtin_amdgcn_mfma_f32_32x32x16_bf16(kf[kc], qf[kc], s, 0, 0, 0);
      __builtin_amdgcn_s_setprio(0);

      // ---- P = exp2(s) directly (|s| <~ 3; no max tracking needed)
      float p[16];
#pragma unroll
      for (int i = 0; i < 16; ++i) p[i] = __builtin_amdgcn_exp2f(s[i]);

      // ---- pack P to bf16 + redistribute halves (distinct regs -> permlane safe)
      unsigned pw[8];
#pragma unroll
      for (int i = 0; i < 8; ++i)
        asm("v_cvt_pk_bf16_f32 %0, %1, %2" : "=v"(pw[i]) : "v"(p[2 * i]), "v"(p[2 * i + 1]));
      asm("v_permlane32_swap_b32 %0, %1" : "+v"(pw[0]), "+v"(pw[2]));
      asm("v_permlane32_swap_b32 %0, %1" : "+v"(pw[1]), "+v"(pw[3]));
      asm("v_permlane32_swap_b32 %0, %1" : "+v"(pw[4]), "+v"(pw[6]));
      asm("v_permlane32_swap_b32 %0, %1" : "+v"(pw[5]), "+v"(pw[7]));
      union { unsigned u[4]; bf16x8 v; } pb0, pb1;
      pb0.u[0] = pw[0]; pb0.u[1] = pw[1]; pb0.u[2] = pw[2]; pb0.u[3] = pw[3];
      pb1.u[0] = pw[4]; pb1.u[1] = pw[5]; pb1.u[2] = pw[6]; pb1.u[3] = pw[7];

      // ---- V^T fragments from LDS (precomputed offsets)
      bf16x8 vf0[2], vf1[2];
#pragma unroll
      for (int kc = 0; kc < 2; ++kc) {
        vf0[kc] = *reinterpret_cast<const bf16x8*>(vl + cbo + roff0 + vch[sub][kc]);
        vf1[kc] = *reinterpret_cast<const bf16x8*>(vl + cbo + roff1 + vch[sub][kc]);
      }

      // ---- O^T += V^T * P ; l via ones-row MFMA
      __builtin_amdgcn_s_setprio(1);
      acc0 = __builtin_amdgcn_mfma_f32_32x32x16_bf16(vf0[0], pb0.v, acc0, 0, 0, 0);
      acc0 = __builtin_amdgcn_mfma_f32_32x32x16_bf16(vf0[1], pb1.v, acc0, 0, 0, 0);
      acc1 = __builtin_amdgcn_mfma_f32_32x32x16_bf16(vf1[0], pb0.v, acc1, 0, 0, 0);
      acc1 = __builtin_amdgcn_mfma_f32_32x32x16_bf16(vf1[1], pb1.v, acc1, 0, 0, 0);
      accl = __builtin_amdgcn_mfma_f32_32x32x16_bf16(onesf, pb0.v, accl, 0, 0, 0);
      accl = __builtin_amdgcn_mfma_f32_32x32x16_bf16(onesf, pb1.v, accl, 0, 0, 0);
      __builtin_amdgcn_s_setprio(0);
    }

    __builtin_amdgcn_sched_barrier(0);
    __builtin_amdgcn_s_barrier();   // all waves done reading buf before next stage overwrites
  }

  // ---- epilogue: l = accl[0]; normalize and store U
  const float inv = 1.0f / accl[0];
  const size_t ubase = (qrow + lq) * QC + h * RK;
#pragma unroll
  for (int g = 0; g < 4; ++g) {
    bf16x4 o0, o1;
#pragma unroll
    for (int j = 0; j < 4; ++j) {
      o0[j] = (bf16_t)(acc0[g * 4 + j] * inv);
      o1[j] = (bf16_t)(acc1[g * 4 + j] * inv);
    }
    const int d0 = g * 8 + hi * 4;
    *reinterpret_cast<bf16x4*>(U + ubase + d0) = o0;
    *reinterpret_cast<bf16x4*>(U + ubase + 32 + d0) = o1;
  }
}

// ---------------------------------------------------------------- launch
extern "C" void kernel_launch(void* const* d_in, const int* in_sizes, int n_in,
                              void* d_out, int out_size, void* d_ws, size_t ws_size,
                              hipStream_t stream) {
  const float* x   = (const float*)d_in[0];
  const float* Wq  = (const float*)d_in[1];
  const float* Wkd = (const float*)d_in[2];
  const float* Wku = (const float*)d_in[3];
  const float* Wvu = (const float*)d_in[4];
  const float* Wo  = (const float*)d_in[5];
  float* out = (float*)d_out;

  char* ws = (char*)d_ws;
  bf16_t* xb    = (bf16_t*)(ws + 0);          // 8192*1024 bf16 = 16 MiB
  bf16_t* CQb   = (bf16_t*)(ws + 16777216);   // 8192*576         9 MiB
  bf16_t* Ub    = (bf16_t*)(ws + 26214400);   // 8192*512         8 MiB
  bf16_t* Wcat  = (bf16_t*)(ws + 34603008);   // 576*1024         1.125 MiB
  bf16_t* Wfe   = (bf16_t*)(ws + 35782656);   // 1024*512         1 MiB
  bf16_t* cTb   = (bf16_t*)(ws + 36831232);   // 4*64*2048        1 MiB

  // Wcat rows 0..63 = Wkv_down (bf16, unscaled); rows 64..575 = Wq_eff (pre-scaled)
  cast_f32_bf16<<<8192, 256, 0, stream>>>(x, xb, BT * DM);
  cast_f32_bf16<<<64, 256, 0, stream>>>(Wkd, Wcat, RK * DM);
  build_wq_eff<<<dim3(4, 8, 16), 256, 0, stream>>>(Wku, Wq, Wcat + (size_t)RK * DM);
  build_w_eff<<<dim3(256, 2), 256, 0, stream>>>(Wo, Wvu, Wfe);

  // [c | q~] = x @ Wcat^T   [8192, 576]; also emits cT (fused transpose)
  gemm_bt<bf16_t, true><<<dim3(BT / 128, 5), 256, 0, stream>>>(xb, Wcat, CQb, cTb, BT, CQW, DM);
  // attention -> U [8192, 512]
  attn_kernel<<<dim3(T_ / 128, NH, B_), 256, 0, stream>>>(CQb, cTb, Ub);
  // out = U @ W_eff^T    [8192, 1024] f32
  gemm_bt<float, false><<<dim3(BT / 128, DM / 128), 256, 0, stream>>>(Ub, Wfe, out, nullptr, BT, DM, QC);
}

// Round 17
// 131.241 us; speedup vs baseline: 1.2422x; 1.1113x over previous
//
#include <hip/hip_runtime.h>
#include <hip/hip_bf16.h>
#include <math.h>

typedef __bf16 bf16_t;
typedef bf16_t bf16x8 __attribute__((ext_vector_type(8)));
typedef bf16_t bf16x4 __attribute__((ext_vector_type(4)));
typedef float f32x4 __attribute__((ext_vector_type(4)));
typedef float f32x16 __attribute__((ext_vector_type(16)));

#define DEV_INLINE __device__ __forceinline__

constexpr int B_ = 4, T_ = 2048, DM = 1024, NH = 8, RK = 64;
constexpr int BT = B_ * T_;        // 8192
constexpr int QC = NH * RK;        // 512
constexpr int CQW = RK + QC;       // 576: fused [c | q~] row width
// softmax scale baked into Wq_eff: (1/sqrt(256)) * log2(e)
#define QK_SCALE 0.09016844f

// ---------------------------------------------------------------- cast f32->bf16 (x)
__global__ void cast_f32_bf16(const float* __restrict__ in, bf16_t* __restrict__ out, int n) {
  int i = (blockIdx.x * blockDim.x + threadIdx.x) * 4;
  if (i >= n) return;
  const float4 v = *reinterpret_cast<const float4*>(in + i);
  bf16x4 o;
  o[0] = (bf16_t)v.x; o[1] = (bf16_t)v.y; o[2] = (bf16_t)v.z; o[3] = (bf16_t)v.w;
  *reinterpret_cast<bf16x4*>(out + i) = o;
}

// ---------------------------------------------------------------- fused prep: cast Wkd + build Wq_eff + build W_eff
// blocks 0..63: Wkd -> Wcat rows 0..63
// blocks 64..575: Wq_eff[(h*64+r), m] = scale * sum_d Wku[(h*256+d)*64+r] * Wq[(h*256+d)*1024+m]
// blocks 576..1087: W_eff[m*512+h*64+r] = sum_d Wo[m*2048+h*256+d] * Wvu[(h*256+d)*64+r]
__global__ __launch_bounds__(256) void prep_kernel(const float* __restrict__ Wkd,
                                                   const float* __restrict__ Wku,
                                                   const float* __restrict__ Wq,
                                                   const float* __restrict__ Wo,
                                                   const float* __restrict__ Wvu,
                                                   bf16_t* __restrict__ Wcat,
                                                   bf16_t* __restrict__ Wfe) {
  const int bx = blockIdx.x;
  if (bx < 64) {
    const int i = (bx * 256 + threadIdx.x) * 4;
    const float4 v = *reinterpret_cast<const float4*>(Wkd + i);
    bf16x4 o;
    o[0] = (bf16_t)v.x; o[1] = (bf16_t)v.y; o[2] = (bf16_t)v.z; o[3] = (bf16_t)v.w;
    *reinterpret_cast<bf16x4*>(Wcat + i) = o;
  } else if (bx < 576) {
    const int idx = bx - 64;
    const int m = (idx & 3) * 256 + threadIdx.x;
    const int h = (idx >> 2) & 7;
    const int r0 = (idx >> 5) * 4;
    float s[4] = {};
    const float* wk = Wku + (size_t)h * 256 * 64 + r0;
    const float* wq = Wq + (size_t)h * 256 * 1024 + m;
    for (int d = 0; d < 256; ++d) {
      float qv = wq[(size_t)d * 1024];
#pragma unroll
      for (int j = 0; j < 4; ++j) s[j] += wk[d * 64 + j] * qv;
    }
    bf16_t* outq = Wcat + (size_t)RK * DM;
#pragma unroll
    for (int j = 0; j < 4; ++j)
      outq[(size_t)(h * 64 + r0 + j) * 1024 + m] = (bf16_t)(s[j] * QK_SCALE);
  } else {
    const int idx = bx - 576;
    const int m0 = (idx & 255) * 4;
    const int h = (idx >> 8) * 4 + (threadIdx.x >> 6);
    const int r = threadIdx.x & 63;
    float s[4] = {};
    const float* wv = Wvu + (size_t)h * 256 * 64 + r;
    const float* wo = Wo + (size_t)m0 * 2048 + h * 256;
    for (int d = 0; d < 256; ++d) {
      const float wvv = wv[d * 64];
#pragma unroll
      for (int j = 0; j < 4; ++j) s[j] += wo[(size_t)j * 2048 + d] * wvv;
    }
#pragma unroll
    for (int j = 0; j < 4; ++j)
      Wfe[(size_t)(m0 + j) * 512 + h * 64 + r] = (bf16_t)s[j];
  }
}

// ---------------------------------------------------------------- GEMM C[M,N] = A[M,K] * B[N,K]^T (bf16 in, f32 acc)
// WRITE_CT: blocks with blockIdx.y==0 / wc==0 own output cols 0..63 (= c);
// they additionally emit the transposed copy cT[b][r][t] (replaces transpose_c).
DEV_INLINE void storeC(float* p, float v) { *p = v; }
DEV_INLINE void storeC(bf16_t* p, float v) { *p = (bf16_t)v; }

DEV_INLINE void async_load16(const void* g, void* l) {
  __builtin_amdgcn_global_load_lds((__attribute__((address_space(1))) void*)g,
                                   (__attribute__((address_space(3))) void*)l, 16, 0, 0);
}

template <typename OutT, bool WRITE_CT>
__global__ __launch_bounds__(256) void gemm_bt(const bf16_t* __restrict__ A,
                                               const bf16_t* __restrict__ Bm,
                                               OutT* __restrict__ C,
                                               bf16_t* __restrict__ CT,
                                               int M, int N, int K) {
  __shared__ bf16_t lA[128 * 32];
  __shared__ bf16_t lB[128 * 32];
  const int tid = threadIdx.x;
  const int lane = tid & 63;
  const int w = tid >> 6;
  const int lo = lane & 15, hi = lane >> 4;
  const int wr = w >> 1, wc = w & 1;
  const size_t row0 = (size_t)blockIdx.x * 128;
  const size_t col0 = (size_t)blockIdx.y * 128;
  const int w64 = w * 64;
  f32x4 acc[4][4] = {};

  for (int k0 = 0; k0 < K; k0 += 32) {
    __syncthreads();
#pragma unroll
    for (int j = 0; j < 2; ++j) {
      const int chunk = j * 256 + w64 + lane;
      const int r = chunk >> 2;
      const int kk = (chunk & 3) * 8;
      const bf16_t* gA = A + (row0 + r) * K + (k0 + kk);
      async_load16(gA, &lA[(size_t)(j * 256 + w64) * 8]);
      size_t rB = col0 + r;
      if (rB >= (size_t)N) rB = N - 1;
      const bf16_t* gB = Bm + rB * K + (k0 + kk);
      async_load16(gB, &lB[(size_t)(j * 256 + w64) * 8]);
    }
    __syncthreads();
    const bf16x8* pA = reinterpret_cast<const bf16x8*>(lA);
    const bf16x8* pB = reinterpret_cast<const bf16x8*>(lB);
    bf16x8 af[4], bfr[4];
#pragma unroll
    for (int m = 0; m < 4; ++m) af[m] = pA[(wr * 64 + m * 16 + lo) * 4 + hi];
#pragma unroll
    for (int n = 0; n < 4; ++n) bfr[n] = pB[(wc * 64 + n * 16 + lo) * 4 + hi];
#pragma unroll
    for (int m = 0; m < 4; ++m)
#pragma unroll
      for (int n = 0; n < 4; ++n)
        acc[m][n] = __builtin_amdgcn_mfma_f32_16x16x32_bf16(af[m], bfr[n], acc[m][n], 0, 0, 0);
  }
#pragma unroll
  for (int m = 0; m < 4; ++m)
#pragma unroll
    for (int n = 0; n < 4; ++n)
#pragma unroll
      for (int q = 0; q < 4; ++q) {
        const size_t row = row0 + wr * 64 + m * 16 + hi * 4 + q;
        const size_t col = col0 + wc * 64 + n * 16 + lo;
        if ((int)col < N) storeC(&C[row * N + col], acc[m][n][q]);
      }
  if (WRITE_CT && blockIdx.y == 0 && wc == 0) {
    // cols 0..63 are c; emit cT[b][r][t] (packed 4 consecutive t per store)
#pragma unroll
    for (int m = 0; m < 4; ++m)
#pragma unroll
      for (int n = 0; n < 4; ++n) {
        bf16x4 o;
#pragma unroll
        for (int q = 0; q < 4; ++q) o[q] = (bf16_t)acc[m][n][q];
        const size_t row = row0 + wr * 64 + m * 16 + hi * 4;   // + q
        const int bb = (int)(row >> 11);            // row / T_
        const int t0 = (int)(row & (T_ - 1));
        const int r = n * 16 + lo;                  // 0..63
        *reinterpret_cast<bf16x4*>(CT + ((size_t)bb * RK + r) * T_ + t0) = o;
      }
  }
}

// ---------------------------------------------------------------- flash attention, no-max softmax + LDS-staged K/V
// r17: r13/r16 staging+swizzle byte-identical; the two 32-kv subs are fused into
// one straight-line body (register-only reorder) -> 2 independent MFMA/softmax
// chains per wave for latency hiding at 2 waves/SIMD.
// 128 q-rows/block, 4 waves; grid 512. l via ones-row MFMA; precomputed offsets.
// CQ [BT,576] = [c | q~ (pre-scaled)], cT [B][64][T], U [BT,512]
__global__ __launch_bounds__(256) void attn_kernel(const bf16_t* __restrict__ CQ,
                                                   const bf16_t* __restrict__ CT,
                                                   bf16_t* __restrict__ U) {
  constexpr int KVT = 64;
  constexpr int NT = T_ / KVT;         // 32 tiles
  constexpr int BUFE = KVT * 64;       // 4096 elements per K (or V) buffer
  __shared__ bf16_t Kl[2][KVT][64];  // [buf][kv][d]   8KB per buf
  __shared__ bf16_t Vl[2][64][KVT];  // [buf][d][kv]   8KB per buf
  const int tid = threadIdx.x;
  const int w = tid >> 6, lane = tid & 63;
  const int lq = lane & 31;        // q column owned by this lane
  const int hi = lane >> 5;        // k-half within fragments
  const int b = blockIdx.z;
  const int h = blockIdx.y;
  const size_t qrow = (size_t)b * T_ + blockIdx.x * 128 + w * 32;
  const bf16_t* __restrict__ cq = CQ + (size_t)b * T_ * CQW;
  const bf16_t* __restrict__ ct = CT + (size_t)b * RK * T_;

  // staging geometry: round q in {0,1}; lane covers row (q*32 + w*8 + lane/8),
  // dest chunk lane&7; source chunk pre-swizzled: (lane&7) ^ (lane>>3)
  const int srow = w * 8 + (lane >> 3);        // + q*32
  const int schunk = (lane & 7) ^ (lane >> 3); // source 16B-chunk (swizzled)

  // Q fragments (B-operand): B[k][q], lane holds Q[q=lq][kc*16 + hi*8 + j]
  bf16x8 qf[4];
#pragma unroll
  for (int kc = 0; kc < 4; ++kc)
    qf[kc] = *reinterpret_cast<const bf16x8*>(
        CQ + (qrow + lq) * CQW + RK + h * RK + kc * 16 + hi * 8);

  f32x16 acc0 = {}, acc1 = {}, accl = {};  // O^T rows 0-31/32-63; accl = l via ones-MFMA

  // ones A-fragment for the l-sum MFMA
  bf16x8 onesf;
#pragma unroll
  for (int j = 0; j < 8; ++j) onesf[j] = (bf16_t)1.0f;

  // precomputed LDS element offsets (chunk XOR is sub-independent: (sub*32+lq)&7 == lq&7)
  const bf16_t* const kl = &Kl[0][0][0];
  const bf16_t* const vl = &Vl[0][0][0];
  const int xr = lq & 7;
  int kch[4], vch[2][2];
#pragma unroll
  for (int kc = 0; kc < 4; ++kc) kch[kc] = ((((kc << 1) | hi)) ^ xr) * 8;
#pragma unroll
  for (int sub = 0; sub < 2; ++sub)
#pragma unroll
    for (int kc = 0; kc < 2; ++kc)
      vch[sub][kc] = ((((sub << 2) | (kc << 1) | hi)) ^ xr) * 8;
  const int roff0 = lq * 64, roff1 = (32 + lq) * 64;   // row bases (K: kv row; V: d row)

  // ---- stage tile 0 (4 gload_lds per wave: 2 K rounds + 2 V rounds)
#pragma unroll
  for (int q = 0; q < 2; ++q) {
    async_load16(cq + (size_t)(q * 32 + srow) * CQW + schunk * 8,
                 &Kl[0][q * 32 + w * 8][0]);
    async_load16(ct + (size_t)(q * 32 + srow) * T_ + schunk * 8,
                 &Vl[0][q * 32 + w * 8][0]);
  }

  for (int t = 0; t < NT; ++t) {
    const int cur = t & 1;
    const int cbo = cur * BUFE;          // current-buffer element offset
    if (t + 1 < NT) {
      const int kvn = (t + 1) * KVT;
#pragma unroll
      for (int q = 0; q < 2; ++q) {
        async_load16(cq + (size_t)(kvn + q * 32 + srow) * CQW + schunk * 8,
                     &Kl[cur ^ 1][q * 32 + w * 8][0]);
        async_load16(ct + (size_t)(q * 32 + srow) * T_ + kvn + schunk * 8,
                     &Vl[cur ^ 1][q * 32 + w * 8][0]);
      }
      asm volatile("s_waitcnt vmcnt(4)" ::: "memory");  // tile t's 4 loads done
    } else {
      asm volatile("s_waitcnt vmcnt(0)" ::: "memory");
    }
    __builtin_amdgcn_s_barrier();
    __builtin_amdgcn_sched_barrier(0);

    // ---- K fragments for BOTH subs (sub A: kv rows lq; sub B: kv rows 32+lq)
    bf16x8 kfA[4], kfB[4];
#pragma unroll
    for (int kc = 0; kc < 4; ++kc) {
      kfA[kc] = *reinterpret_cast<const bf16x8*>(kl + cbo + roff0 + kch[kc]);
      kfB[kc] = *reinterpret_cast<const bf16x8*>(kl + cbo + roff1 + kch[kc]);
    }
    // ---- S^T = K * Q^T, two independent chains
    f32x16 sA = {}, sB = {};
    __builtin_amdgcn_s_setprio(1);
#pragma unroll
    for (int kc = 0; kc < 4; ++kc) {
      sA = __builtin_amdgcn_mfma_f32_32x32x16_bf16(kfA[kc], qf[kc], sA, 0, 0, 0);
      sB = __builtin_amdgcn_mfma_f32_32x32x16_bf16(kfB[kc], qf[kc], sB, 0, 0, 0);
    }
    __builtin_amdgcn_s_setprio(0);

    // ---- P = exp2(s) for both subs
    float pA[16], pB[16];
#pragma unroll
    for (int i = 0; i < 16; ++i) { pA[i] = __builtin_amdgcn_exp2f(sA[i]); pB[i] = __builtin_amdgcn_exp2f(sB[i]); }

    // ---- pack both to bf16 + redistribute halves (distinct regs -> permlane safe)
    unsigned pwA[8], pwB[8];
#pragma unroll
    for (int i = 0; i < 8; ++i) {
      asm("v_cvt_pk_bf16_f32 %0, %1, %2" : "=v"(pwA[i]) : "v"(pA[2 * i]), "v"(pA[2 * i + 1]));
      asm("v_cvt_pk_bf16_f32 %0, %1, %2" : "=v"(pwB[i]) : "v"(pB[2 * i]), "v"(pB[2 * i + 1]));
    }
    asm("v_permlane32_swap_b32 %0, %1" : "+v"(pwA[0]), "+v"(pwA[2]));
    asm("v_permlane32_swap_b32 %0, %1" : "+v"(pwA[1]), "+v"(pwA[3]));
    asm("v_permlane32_swap_b32 %0, %1" : "+v"(pwA[4]), "+v"(pwA[6]));
    asm("v_permlane32_swap_b32 %0, %1" : "+v"(pwA[5]), "+v"(pwA[7]));
    asm("v_permlane32_swap_b32 %0, %1" : "+v"(pwB[0]), "+v"(pwB[2]));
    asm("v_permlane32_swap_b32 %0, %1" : "+v"(pwB[1]), "+v"(pwB[3]));
    asm("v_permlane32_swap_b32 %0, %1" : "+v"(pwB[4]), "+v"(pwB[6]));
    asm("v_permlane32_swap_b32 %0, %1" : "+v"(pwB[5]), "+v"(pwB[7]));
    union { unsigned u[4]; bf16x8 v; } pbA0, pbA1, pbB0, pbB1;
    pbA0.u[0] = pwA[0]; pbA0.u[1] = pwA[1]; pbA0.u[2] = pwA[2]; pbA0.u[3] = pwA[3];
    pbA1.u[0] = pwA[4]; pbA1.u[1] = pwA[5]; pbA1.u[2] = pwA[6]; pbA1.u[3] = pwA[7];
    pbB0.u[0] = pwB[0]; pbB0.u[1] = pwB[1]; pbB0.u[2] = pwB[2]; pbB0.u[3] = pwB[3];
    pbB1.u[0] = pwB[4]; pbB1.u[1] = pwB[5]; pbB1.u[2] = pwB[6]; pbB1.u[3] = pwB[7];

    // ---- V^T fragments for both subs
    bf16x8 vfA0[2], vfA1[2], vfB0[2], vfB1[2];
#pragma unroll
    for (int kc = 0; kc < 2; ++kc) {
      vfA0[kc] = *reinterpret_cast<const bf16x8*>(vl + cbo + roff0 + vch[0][kc]);
      vfA1[kc] = *reinterpret_cast<const bf16x8*>(vl + cbo + roff1 + vch[0][kc]);
      vfB0[kc] = *reinterpret_cast<const bf16x8*>(vl + cbo + roff0 + vch[1][kc]);
      vfB1[kc] = *reinterpret_cast<const bf16x8*>(vl + cbo + roff1 + vch[1][kc]);
    }

    // ---- O^T += V^T * P (both subs) ; l via ones-row MFMA
    __builtin_amdgcn_s_setprio(1);
    acc0 = __builtin_amdgcn_mfma_f32_32x32x16_bf16(vfA0[0], pbA0.v, acc0, 0, 0, 0);
    acc1 = __builtin_amdgcn_mfma_f32_32x32x16_bf16(vfA1[0], pbA0.v, acc1, 0, 0, 0);
    acc0 = __builtin_amdgcn_mfma_f32_32x32x16_bf16(vfA0[1], pbA1.v, acc0, 0, 0, 0);
    acc1 = __builtin_amdgcn_mfma_f32_32x32x16_bf16(vfA1[1], pbA1.v, acc1, 0, 0, 0);
    accl = __builtin_amdgcn_mfma_f32_32x32x16_bf16(onesf, pbA0.v, accl, 0, 0, 0);
    accl = __builtin_amdgcn_mfma_f32_32x32x16_bf16(onesf, pbA1.v, accl, 0, 0, 0);
    acc0 = __builtin_amdgcn_mfma_f32_32x32x16_bf16(vfB0[0], pbB0.v, acc0, 0, 0, 0);
    acc1 = __builtin_amdgcn_mfma_f32_32x32x16_bf16(vfB1[0], pbB0.v, acc1, 0, 0, 0);
    acc0 = __builtin_amdgcn_mfma_f32_32x32x16_bf16(vfB0[1], pbB1.v, acc0, 0, 0, 0);
    acc1 = __builtin_amdgcn_mfma_f32_32x32x16_bf16(vfB1[1], pbB1.v, acc1, 0, 0, 0);
    accl = __builtin_amdgcn_mfma_f32_32x32x16_bf16(onesf, pbB0.v, accl, 0, 0, 0);
    accl = __builtin_amdgcn_mfma_f32_32x32x16_bf16(onesf, pbB1.v, accl, 0, 0, 0);
    __builtin_amdgcn_s_setprio(0);

    __builtin_amdgcn_sched_barrier(0);
    __builtin_amdgcn_s_barrier();   // all waves done reading buf before next stage overwrites
  }

  // ---- epilogue: l = accl[0]; normalize and store U
  const float inv = 1.0f / accl[0];
  const size_t ubase = (qrow + lq) * QC + h * RK;
#pragma unroll
  for (int g = 0; g < 4; ++g) {
    bf16x4 o0, o1;
#pragma unroll
    for (int j = 0; j < 4; ++j) {
      o0[j] = (bf16_t)(acc0[g * 4 + j] * inv);
      o1[j] = (bf16_t)(acc1[g * 4 + j] * inv);
    }
    const int d0 = g * 8 + hi * 4;
    *reinterpret_cast<bf16x4*>(U + ubase + d0) = o0;
    *reinterpret_cast<bf16x4*>(U + ubase + 32 + d0) = o1;
  }
}

// ---------------------------------------------------------------- launch
extern "C" void kernel_launch(void* const* d_in, const int* in_sizes, int n_in,
                              void* d_out, int out_size, void* d_ws, size_t ws_size,
                              hipStream_t stream) {
  const float* x   = (const float*)d_in[0];
  const float* Wq  = (const float*)d_in[1];
  const float* Wkd = (const float*)d_in[2];
  const float* Wku = (const float*)d_in[3];
  const float* Wvu = (const float*)d_in[4];
  const float* Wo  = (const float*)d_in[5];
  float* out = (float*)d_out;

  char* ws = (char*)d_ws;
  bf16_t* xb    = (bf16_t*)(ws + 0);          // 8192*1024 bf16 = 16 MiB
  bf16_t* CQb   = (bf16_t*)(ws + 16777216);   // 8192*576         9 MiB
  bf16_t* Ub    = (bf16_t*)(ws + 26214400);   // 8192*512         8 MiB
  bf16_t* Wcat  = (bf16_t*)(ws + 34603008);   // 576*1024         1.125 MiB
  bf16_t* Wfe   = (bf16_t*)(ws + 35782656);   // 1024*512         1 MiB
  bf16_t* cTb   = (bf16_t*)(ws + 36831232);   // 4*64*2048        1 MiB

  // Wcat rows 0..63 = Wkv_down (bf16, unscaled); rows 64..575 = Wq_eff (pre-scaled)
  cast_f32_bf16<<<8192, 256, 0, stream>>>(x, xb, BT * DM);
  prep_kernel<<<1088, 256, 0, stream>>>(Wkd, Wku, Wq, Wo, Wvu, Wcat, Wfe);

  // [c | q~] = x @ Wcat^T   [8192, 576]; also emits cT (fused transpose)
  gemm_bt<bf16_t, true><<<dim3(BT / 128, 5), 256, 0, stream>>>(xb, Wcat, CQb, cTb, BT, CQW, DM);
  // attention -> U [8192, 512]
  attn_kernel<<<dim3(T_ / 128, NH, B_), 256, 0, stream>>>(CQb, cTb, Ub);
  // out = U @ W_eff^T    [8192, 1024] f32
  gemm_bt<float, false><<<dim3(BT / 128, DM / 128), 256, 0, stream>>>(Ub, Wfe, out, nullptr, BT, DM, QC);
}

// Round 18
// 123.951 us; speedup vs baseline: 1.3153x; 1.0588x over previous
//
#include <hip/hip_runtime.h>
#include <hip/hip_bf16.h>
#include <math.h>

typedef __bf16 bf16_t;
typedef bf16_t bf16x8 __attribute__((ext_vector_type(8)));
typedef bf16_t bf16x4 __attribute__((ext_vector_type(4)));
typedef float f32x4 __attribute__((ext_vector_type(4)));
typedef float f32x16 __attribute__((ext_vector_type(16)));

#define DEV_INLINE __device__ __forceinline__

constexpr int B_ = 4, T_ = 2048, DM = 1024, NH = 8, RK = 64;
constexpr int BT = B_ * T_;        // 8192
constexpr int QC = NH * RK;        // 512
constexpr int CQW = RK + QC;       // 576: fused [c | q~] row width
// softmax scale baked into Wq_eff: (1/sqrt(256)) * log2(e)
#define QK_SCALE 0.09016844f

// ---------------------------------------------------------------- fused prep:
// blocks 0..63:      cast Wkd -> Wcat rows 0..63
// blocks 64..575:    Wq_eff[(h*64+r), m] = scale * sum_d Wku[(h*256+d)*64+r] * Wq[(h*256+d)*1024+m]
// blocks 576..1087:  W_eff[m*512+h*64+r] = sum_d Wo[m*2048+h*256+d] * Wvu[(h*256+d)*64+r]
// blocks 1088..9279: cast x -> xb (8192 blocks, 1024 f32 each)
__global__ __launch_bounds__(256) void prep_kernel(const float* __restrict__ x,
                                                   const float* __restrict__ Wkd,
                                                   const float* __restrict__ Wku,
                                                   const float* __restrict__ Wq,
                                                   const float* __restrict__ Wo,
                                                   const float* __restrict__ Wvu,
                                                   bf16_t* __restrict__ xb,
                                                   bf16_t* __restrict__ Wcat,
                                                   bf16_t* __restrict__ Wfe) {
  const int bx = blockIdx.x;
  if (bx >= 1088) {
    const size_t i = ((size_t)(bx - 1088) * 256 + threadIdx.x) * 4;
    const float4 v = *reinterpret_cast<const float4*>(x + i);
    bf16x4 o;
    o[0] = (bf16_t)v.x; o[1] = (bf16_t)v.y; o[2] = (bf16_t)v.z; o[3] = (bf16_t)v.w;
    *reinterpret_cast<bf16x4*>(xb + i) = o;
  } else if (bx < 64) {
    const int i = (bx * 256 + threadIdx.x) * 4;
    const float4 v = *reinterpret_cast<const float4*>(Wkd + i);
    bf16x4 o;
    o[0] = (bf16_t)v.x; o[1] = (bf16_t)v.y; o[2] = (bf16_t)v.z; o[3] = (bf16_t)v.w;
    *reinterpret_cast<bf16x4*>(Wcat + i) = o;
  } else if (bx < 576) {
    const int idx = bx - 64;
    const int m = (idx & 3) * 256 + threadIdx.x;
    const int h = (idx >> 2) & 7;
    const int r0 = (idx >> 5) * 4;
    float s[4] = {};
    const float* wk = Wku + (size_t)h * 256 * 64 + r0;
    const float* wq = Wq + (size_t)h * 256 * 1024 + m;
    for (int d = 0; d < 256; ++d) {
      float qv = wq[(size_t)d * 1024];
#pragma unroll
      for (int j = 0; j < 4; ++j) s[j] += wk[d * 64 + j] * qv;
    }
    bf16_t* outq = Wcat + (size_t)RK * DM;
#pragma unroll
    for (int j = 0; j < 4; ++j)
      outq[(size_t)(h * 64 + r0 + j) * 1024 + m] = (bf16_t)(s[j] * QK_SCALE);
  } else {
    const int idx = bx - 576;
    const int m0 = (idx & 255) * 4;
    const int h = (idx >> 8) * 4 + (threadIdx.x >> 6);
    const int r = threadIdx.x & 63;
    float s[4] = {};
    const float* wv = Wvu + (size_t)h * 256 * 64 + r;
    const float* wo = Wo + (size_t)m0 * 2048 + h * 256;
    for (int d = 0; d < 256; ++d) {
      const float wvv = wv[d * 64];
#pragma unroll
      for (int j = 0; j < 4; ++j) s[j] += wo[(size_t)j * 2048 + d] * wvv;
    }
#pragma unroll
    for (int j = 0; j < 4; ++j)
      Wfe[(size_t)(m0 + j) * 512 + h * 64 + r] = (bf16_t)s[j];
  }
}

// ---------------------------------------------------------------- GEMM C[M,N] = A[M,K] * B[N,K]^T (bf16 in, f32 acc)
// WRITE_CT: blocks with blockIdx.y==0 / wc==0 own output cols 0..63 (= c);
// they additionally emit the transposed copy cT[b][r][t] (replaces transpose_c).
DEV_INLINE void storeC(float* p, float v) { *p = v; }
DEV_INLINE void storeC(bf16_t* p, float v) { *p = (bf16_t)v; }

DEV_INLINE void async_load16(const void* g, void* l) {
  __builtin_amdgcn_global_load_lds((__attribute__((address_space(1))) void*)g,
                                   (__attribute__((address_space(3))) void*)l, 16, 0, 0);
}

template <typename OutT, bool WRITE_CT>
__global__ __launch_bounds__(256) void gemm_bt(const bf16_t* __restrict__ A,
                                               const bf16_t* __restrict__ Bm,
                                               OutT* __restrict__ C,
                                               bf16_t* __restrict__ CT,
                                               int M, int N, int K) {
  __shared__ bf16_t lA[128 * 32];
  __shared__ bf16_t lB[128 * 32];
  const int tid = threadIdx.x;
  const int lane = tid & 63;
  const int w = tid >> 6;
  const int lo = lane & 15, hi = lane >> 4;
  const int wr = w >> 1, wc = w & 1;
  const size_t row0 = (size_t)blockIdx.x * 128;
  const size_t col0 = (size_t)blockIdx.y * 128;
  const int w64 = w * 64;
  f32x4 acc[4][4] = {};

  for (int k0 = 0; k0 < K; k0 += 32) {
    __syncthreads();
#pragma unroll
    for (int j = 0; j < 2; ++j) {
      const int chunk = j * 256 + w64 + lane;
      const int r = chunk >> 2;
      const int kk = (chunk & 3) * 8;
      const bf16_t* gA = A + (row0 + r) * K + (k0 + kk);
      async_load16(gA, &lA[(size_t)(j * 256 + w64) * 8]);
      size_t rB = col0 + r;
      if (rB >= (size_t)N) rB = N - 1;
      const bf16_t* gB = Bm + rB * K + (k0 + kk);
      async_load16(gB, &lB[(size_t)(j * 256 + w64) * 8]);
    }
    __syncthreads();
    const bf16x8* pA = reinterpret_cast<const bf16x8*>(lA);
    const bf16x8* pB = reinterpret_cast<const bf16x8*>(lB);
    bf16x8 af[4], bfr[4];
#pragma unroll
    for (int m = 0; m < 4; ++m) af[m] = pA[(wr * 64 + m * 16 + lo) * 4 + hi];
#pragma unroll
    for (int n = 0; n < 4; ++n) bfr[n] = pB[(wc * 64 + n * 16 + lo) * 4 + hi];
#pragma unroll
    for (int m = 0; m < 4; ++m)
#pragma unroll
      for (int n = 0; n < 4; ++n)
        acc[m][n] = __builtin_amdgcn_mfma_f32_16x16x32_bf16(af[m], bfr[n], acc[m][n], 0, 0, 0);
  }
#pragma unroll
  for (int m = 0; m < 4; ++m)
#pragma unroll
    for (int n = 0; n < 4; ++n)
#pragma unroll
      for (int q = 0; q < 4; ++q) {
        const size_t row = row0 + wr * 64 + m * 16 + hi * 4 + q;
        const size_t col = col0 + wc * 64 + n * 16 + lo;
        if ((int)col < N) storeC(&C[row * N + col], acc[m][n][q]);
      }
  if (WRITE_CT && blockIdx.y == 0 && wc == 0) {
    // cols 0..63 are c; emit cT[b][r][t] (packed 4 consecutive t per store)
#pragma unroll
    for (int m = 0; m < 4; ++m)
#pragma unroll
      for (int n = 0; n < 4; ++n) {
        bf16x4 o;
#pragma unroll
        for (int q = 0; q < 4; ++q) o[q] = (bf16_t)acc[m][n][q];
        const size_t row = row0 + wr * 64 + m * 16 + hi * 4;   // + q
        const int bb = (int)(row >> 11);            // row / T_
        const int t0 = (int)(row & (T_ - 1));
        const int r = n * 16 + lo;                  // 0..63
        *reinterpret_cast<bf16x4*>(CT + ((size_t)bb * RK + r) * T_ + t0) = o;
      }
  }
}

// ---------------------------------------------------------------- flash attention, no-max softmax + LDS-staged K/V
// r18: byte-exact r13 loop (best measured attn: 54.6us; no setprio, no sub-fusion).
// 128 q-rows/block, 4 waves; grid 512. l via ones-row MFMA; precomputed offsets.
// CQ [BT,576] = [c | q~ (pre-scaled)], cT [B][64][T], U [BT,512]
__global__ __launch_bounds__(256) void attn_kernel(const bf16_t* __restrict__ CQ,
                                                   const bf16_t* __restrict__ CT,
                                                   bf16_t* __restrict__ U) {
  constexpr int KVT = 64;
  constexpr int NT = T_ / KVT;         // 32 tiles
  constexpr int BUFE = KVT * 64;       // 4096 elements per K (or V) buffer
  __shared__ bf16_t Kl[2][KVT][64];  // [buf][kv][d]   8KB per buf
  __shared__ bf16_t Vl[2][64][KVT];  // [buf][d][kv]   8KB per buf
  const int tid = threadIdx.x;
  const int w = tid >> 6, lane = tid & 63;
  const int lq = lane & 31;        // q column owned by this lane
  const int hi = lane >> 5;        // k-half within fragments
  const int b = blockIdx.z;
  const int h = blockIdx.y;
  const size_t qrow = (size_t)b * T_ + blockIdx.x * 128 + w * 32;
  const bf16_t* __restrict__ cq = CQ + (size_t)b * T_ * CQW;
  const bf16_t* __restrict__ ct = CT + (size_t)b * RK * T_;

  // staging geometry: round q in {0,1}; lane covers row (q*32 + w*8 + lane/8),
  // dest chunk lane&7; source chunk pre-swizzled: (lane&7) ^ (lane>>3)
  const int srow = w * 8 + (lane >> 3);        // + q*32
  const int schunk = (lane & 7) ^ (lane >> 3); // source 16B-chunk (swizzled)

  // Q fragments (B-operand): B[k][q], lane holds Q[q=lq][kc*16 + hi*8 + j]
  bf16x8 qf[4];
#pragma unroll
  for (int kc = 0; kc < 4; ++kc)
    qf[kc] = *reinterpret_cast<const bf16x8*>(
        CQ + (qrow + lq) * CQW + RK + h * RK + kc * 16 + hi * 8);

  f32x16 acc0 = {}, acc1 = {}, accl = {};  // O^T rows 0-31/32-63; accl = l via ones-MFMA

  // ones A-fragment for the l-sum MFMA
  bf16x8 onesf;
#pragma unroll
  for (int j = 0; j < 8; ++j) onesf[j] = (bf16_t)1.0f;

  // precomputed LDS element offsets (chunk XOR is sub-independent: (sub*32+lq)&7 == lq&7)
  const bf16_t* const kl = &Kl[0][0][0];
  const bf16_t* const vl = &Vl[0][0][0];
  const int xr = lq & 7;
  int kch[4], vch[2][2];
#pragma unroll
  for (int kc = 0; kc < 4; ++kc) kch[kc] = ((((kc << 1) | hi)) ^ xr) * 8;
#pragma unroll
  for (int sub = 0; sub < 2; ++sub)
#pragma unroll
    for (int kc = 0; kc < 2; ++kc)
      vch[sub][kc] = ((((sub << 2) | (kc << 1) | hi)) ^ xr) * 8;
  const int roff0 = lq * 64, roff1 = (32 + lq) * 64;   // row bases (K: kv row; V: d row)

  // ---- stage tile 0 (4 gload_lds per wave: 2 K rounds + 2 V rounds)
#pragma unroll
  for (int q = 0; q < 2; ++q) {
    async_load16(cq + (size_t)(q * 32 + srow) * CQW + schunk * 8,
                 &Kl[0][q * 32 + w * 8][0]);
    async_load16(ct + (size_t)(q * 32 + srow) * T_ + schunk * 8,
                 &Vl[0][q * 32 + w * 8][0]);
  }

  for (int t = 0; t < NT; ++t) {
    const int cur = t & 1;
    const int cbo = cur * BUFE;          // current-buffer element offset
    if (t + 1 < NT) {
      const int kvn = (t + 1) * KVT;
#pragma unroll
      for (int q = 0; q < 2; ++q) {
        async_load16(cq + (size_t)(kvn + q * 32 + srow) * CQW + schunk * 8,
                     &Kl[cur ^ 1][q * 32 + w * 8][0]);
        async_load16(ct + (size_t)(q * 32 + srow) * T_ + kvn + schunk * 8,
                     &Vl[cur ^ 1][q * 32 + w * 8][0]);
      }
      asm volatile("s_waitcnt vmcnt(4)" ::: "memory");  // tile t's 4 loads done
    } else {
      asm volatile("s_waitcnt vmcnt(0)" ::: "memory");
    }
    __builtin_amdgcn_s_barrier();
    __builtin_amdgcn_sched_barrier(0);

#pragma unroll
    for (int sub = 0; sub < 2; ++sub) {
      // ---- K fragments from LDS (precomputed offsets)
      const int krb = cbo + (sub ? roff1 : roff0);
      bf16x8 kf[4];
#pragma unroll
      for (int kc = 0; kc < 4; ++kc)
        kf[kc] = *reinterpret_cast<const bf16x8*>(kl + krb + kch[kc]);
      // ---- S^T = K * Q^T
      f32x16 s = {};
#pragma unroll
      for (int kc = 0; kc < 4; ++kc)
        s = __builtin_amdgcn_mfma_f32_32x32x16_bf16(kf[kc], qf[kc], s, 0, 0, 0);

      // ---- P = exp2(s) directly (|s| <~ 3; no max tracking needed)
      float p[16];
#pragma unroll
      for (int i = 0; i < 16; ++i) p[i] = __builtin_amdgcn_exp2f(s[i]);

      // ---- pack P to bf16 + redistribute halves (distinct regs -> permlane safe)
      unsigned pw[8];
#pragma unroll
      for (int i = 0; i < 8; ++i)
        asm("v_cvt_pk_bf16_f32 %0, %1, %2" : "=v"(pw[i]) : "v"(p[2 * i]), "v"(p[2 * i + 1]));
      asm("v_permlane32_swap_b32 %0, %1" : "+v"(pw[0]), "+v"(pw[2]));
      asm("v_permlane32_swap_b32 %0, %1" : "+v"(pw[1]), "+v"(pw[3]));
      asm("v_permlane32_swap_b32 %0, %1" : "+v"(pw[4]), "+v"(pw[6]));
      asm("v_permlane32_swap_b32 %0, %1" : "+v"(pw[5]), "+v"(pw[7]));
      union { unsigned u[4]; bf16x8 v; } pb0, pb1;
      pb0.u[0] = pw[0]; pb0.u[1] = pw[1]; pb0.u[2] = pw[2]; pb0.u[3] = pw[3];
      pb1.u[0] = pw[4]; pb1.u[1] = pw[5]; pb1.u[2] = pw[6]; pb1.u[3] = pw[7];

      // ---- V^T fragments from LDS (precomputed offsets)
      bf16x8 vf0[2], vf1[2];
#pragma unroll
      for (int kc = 0; kc < 2; ++kc) {
        vf0[kc] = *reinterpret_cast<const bf16x8*>(vl + cbo + roff0 + vch[sub][kc]);
        vf1[kc] = *reinterpret_cast<const bf16x8*>(vl + cbo + roff1 + vch[sub][kc]);
      }

      // ---- O^T += V^T * P ; l via ones-row MFMA
      acc0 = __builtin_amdgcn_mfma_f32_32x32x16_bf16(vf0[0], pb0.v, acc0, 0, 0, 0);
      acc0 = __builtin_amdgcn_mfma_f32_32x32x16_bf16(vf0[1], pb1.v, acc0, 0, 0, 0);
      acc1 = __builtin_amdgcn_mfma_f32_32x32x16_bf16(vf1[0], pb0.v, acc1, 0, 0, 0);
      acc1 = __builtin_amdgcn_mfma_f32_32x32x16_bf16(vf1[1], pb1.v, acc1, 0, 0, 0);
      accl = __builtin_amdgcn_mfma_f32_32x32x16_bf16(onesf, pb0.v, accl, 0, 0, 0);
      accl = __builtin_amdgcn_mfma_f32_32x32x16_bf16(onesf, pb1.v, accl, 0, 0, 0);
    }

    __builtin_amdgcn_sched_barrier(0);
    __builtin_amdgcn_s_barrier();   // all waves done reading buf before next stage overwrites
  }

  // ---- epilogue: l = accl[0]; normalize and store U
  const float inv = 1.0f / accl[0];
  const size_t ubase = (qrow + lq) * QC + h * RK;
#pragma unroll
  for (int g = 0; g < 4; ++g) {
    bf16x4 o0, o1;
#pragma unroll
    for (int j = 0; j < 4; ++j) {
      o0[j] = (bf16_t)(acc0[g * 4 + j] * inv);
      o1[j] = (bf16_t)(acc1[g * 4 + j] * inv);
    }
    const int d0 = g * 8 + hi * 4;
    *reinterpret_cast<bf16x4*>(U + ubase + d0) = o0;
    *reinterpret_cast<bf16x4*>(U + ubase + 32 + d0) = o1;
  }
}

// ---------------------------------------------------------------- launch
extern "C" void kernel_launch(void* const* d_in, const int* in_sizes, int n_in,
                              void* d_out, int out_size, void* d_ws, size_t ws_size,
                              hipStream_t stream) {
  const float* x   = (const float*)d_in[0];
  const float* Wq  = (const float*)d_in[1];
  const float* Wkd = (const float*)d_in[2];
  const float* Wku = (const float*)d_in[3];
  const float* Wvu = (const float*)d_in[4];
  const float* Wo  = (const float*)d_in[5];
  float* out = (float*)d_out;

  char* ws = (char*)d_ws;
  bf16_t* xb    = (bf16_t*)(ws + 0);          // 8192*1024 bf16 = 16 MiB
  bf16_t* CQb   = (bf16_t*)(ws + 16777216);   // 8192*576         9 MiB
  bf16_t* Ub    = (bf16_t*)(ws + 26214400);   // 8192*512         8 MiB
  bf16_t* Wcat  = (bf16_t*)(ws + 34603008);   // 576*1024         1.125 MiB
  bf16_t* Wfe   = (bf16_t*)(ws + 35782656);   // 1024*512         1 MiB
  bf16_t* cTb   = (bf16_t*)(ws + 36831232);   // 4*64*2048        1 MiB

  // one fused prep: x-cast + Wkd-cast + Wq_eff + W_eff
  prep_kernel<<<1088 + 8192, 256, 0, stream>>>(x, Wkd, Wku, Wq, Wo, Wvu, xb, Wcat, Wfe);

  // [c | q~] = x @ Wcat^T   [8192, 576]; also emits cT (fused transpose)
  gemm_bt<bf16_t, true><<<dim3(BT / 128, 5), 256, 0, stream>>>(xb, Wcat, CQb, cTb, BT, CQW, DM);
  // attention -> U [8192, 512]
  attn_kernel<<<dim3(T_ / 128, NH, B_), 256, 0, stream>>>(CQb, cTb, Ub);
  // out = U @ W_eff^T    [8192, 1024] f32
  gemm_bt<float, false><<<dim3(BT / 128, DM / 128), 256, 0, stream>>>(Ub, Wfe, out, nullptr, BT, DM, QC);
}

// Round 20
// 123.899 us; speedup vs baseline: 1.3158x; 1.0004x over previous
//
#include <hip/hip_runtime.h>
#include <hip/hip_bf16.h>
#include <math.h>

typedef __bf16 bf16_t;
typedef bf16_t bf16x8 __attribute__((ext_vector_type(8)));
typedef bf16_t bf16x4 __attribute__((ext_vector_type(4)));
typedef float f32x4 __attribute__((ext_vector_type(4)));
typedef float f32x16 __attribute__((ext_vector_type(16)));

#define DEV_INLINE __device__ __forceinline__

constexpr int B_ = 4, T_ = 2048, DM = 1024, NH = 8, RK = 64;
constexpr int BT = B_ * T_;        // 8192
constexpr int QC = NH * RK;        // 512
constexpr int CQW = RK + QC;       // 576: fused [c | q~] row width
// softmax scale baked into Wq_eff: (1/sqrt(256)) * log2(e)
#define QK_SCALE 0.09016844f

// ---------------------------------------------------------------- fused prep:
// blocks 0..63:      cast Wkd -> Wcat rows 0..63
// blocks 64..575:    Wq_eff[(h*64+r), m] = scale * sum_d Wku[(h*256+d)*64+r] * Wq[(h*256+d)*1024+m]
// blocks 576..1087:  W_eff[m*512+h*64+r] = sum_d Wo[m*2048+h*256+d] * Wvu[(h*256+d)*64+r]
// blocks 1088..9279: cast x -> xb (8192 blocks, 1024 f32 each)
__global__ __launch_bounds__(256) void prep_kernel(const float* __restrict__ x,
                                                   const float* __restrict__ Wkd,
                                                   const float* __restrict__ Wku,
                                                   const float* __restrict__ Wq,
                                                   const float* __restrict__ Wo,
                                                   const float* __restrict__ Wvu,
                                                   bf16_t* __restrict__ xb,
                                                   bf16_t* __restrict__ Wcat,
                                                   bf16_t* __restrict__ Wfe) {
  const int bx = blockIdx.x;
  if (bx >= 1088) {
    const size_t i = ((size_t)(bx - 1088) * 256 + threadIdx.x) * 4;
    const float4 v = *reinterpret_cast<const float4*>(x + i);
    bf16x4 o;
    o[0] = (bf16_t)v.x; o[1] = (bf16_t)v.y; o[2] = (bf16_t)v.z; o[3] = (bf16_t)v.w;
    *reinterpret_cast<bf16x4*>(xb + i) = o;
  } else if (bx < 64) {
    const int i = (bx * 256 + threadIdx.x) * 4;
    const float4 v = *reinterpret_cast<const float4*>(Wkd + i);
    bf16x4 o;
    o[0] = (bf16_t)v.x; o[1] = (bf16_t)v.y; o[2] = (bf16_t)v.z; o[3] = (bf16_t)v.w;
    *reinterpret_cast<bf16x4*>(Wcat + i) = o;
  } else if (bx < 576) {
    const int idx = bx - 64;
    const int m = (idx & 3) * 256 + threadIdx.x;
    const int h = (idx >> 2) & 7;
    const int r0 = (idx >> 5) * 4;
    float s[4] = {};
    const float* wk = Wku + (size_t)h * 256 * 64 + r0;
    const float* wq = Wq + (size_t)h * 256 * 1024 + m;
    for (int d = 0; d < 256; ++d) {
      float qv = wq[(size_t)d * 1024];
#pragma unroll
      for (int j = 0; j < 4; ++j) s[j] += wk[d * 64 + j] * qv;
    }
    bf16_t* outq = Wcat + (size_t)RK * DM;
#pragma unroll
    for (int j = 0; j < 4; ++j)
      outq[(size_t)(h * 64 + r0 + j) * 1024 + m] = (bf16_t)(s[j] * QK_SCALE);
  } else {
    const int idx = bx - 576;
    const int m0 = (idx & 255) * 4;
    const int h = (idx >> 8) * 4 + (threadIdx.x >> 6);
    const int r = threadIdx.x & 63;
    float s[4] = {};
    const float* wv = Wvu + (size_t)h * 256 * 64 + r;
    const float* wo = Wo + (size_t)m0 * 2048 + h * 256;
    for (int d = 0; d < 256; ++d) {
      const float wvv = wv[d * 64];
#pragma unroll
      for (int j = 0; j < 4; ++j) s[j] += wo[(size_t)j * 2048 + d] * wvv;
    }
#pragma unroll
    for (int j = 0; j < 4; ++j)
      Wfe[(size_t)(m0 + j) * 512 + h * 64 + r] = (bf16_t)s[j];
  }
}

// ---------------------------------------------------------------- GEMM C[M,N] = A[M,K] * B[N,K]^T (bf16 in, f32 acc)
// WRITE_CT: blocks with blockIdx.y==0 / wc==0 own output cols 0..63 (= c);
// they additionally emit the transposed copy cT[b][r][t] (replaces transpose_c).
DEV_INLINE void storeC(float* p, float v) { *p = v; }
DEV_INLINE void storeC(bf16_t* p, float v) { *p = (bf16_t)v; }

DEV_INLINE void async_load16(const void* g, void* l) {
  __builtin_amdgcn_global_load_lds((__attribute__((address_space(1))) void*)g,
                                   (__attribute__((address_space(3))) void*)l, 16, 0, 0);
}

template <typename OutT, bool WRITE_CT>
__global__ __launch_bounds__(256) void gemm_bt(const bf16_t* __restrict__ A,
                                               const bf16_t* __restrict__ Bm,
                                               OutT* __restrict__ C,
                                               bf16_t* __restrict__ CT,
                                               int M, int N, int K) {
  __shared__ bf16_t lA[128 * 32];
  __shared__ bf16_t lB[128 * 32];
  const int tid = threadIdx.x;
  const int lane = tid & 63;
  const int w = tid >> 6;
  const int lo = lane & 15, hi = lane >> 4;
  const int wr = w >> 1, wc = w & 1;
  const size_t row0 = (size_t)blockIdx.x * 128;
  const size_t col0 = (size_t)blockIdx.y * 128;
  const int w64 = w * 64;
  f32x4 acc[4][4] = {};

  for (int k0 = 0; k0 < K; k0 += 32) {
    __syncthreads();
#pragma unroll
    for (int j = 0; j < 2; ++j) {
      const int chunk = j * 256 + w64 + lane;
      const int r = chunk >> 2;
      const int kk = (chunk & 3) * 8;
      const bf16_t* gA = A + (row0 + r) * K + (k0 + kk);
      async_load16(gA, &lA[(size_t)(j * 256 + w64) * 8]);
      size_t rB = col0 + r;
      if (rB >= (size_t)N) rB = N - 1;
      const bf16_t* gB = Bm + rB * K + (k0 + kk);
      async_load16(gB, &lB[(size_t)(j * 256 + w64) * 8]);
    }
    __syncthreads();
    const bf16x8* pA = reinterpret_cast<const bf16x8*>(lA);
    const bf16x8* pB = reinterpret_cast<const bf16x8*>(lB);
    bf16x8 af[4], bfr[4];
#pragma unroll
    for (int m = 0; m < 4; ++m) af[m] = pA[(wr * 64 + m * 16 + lo) * 4 + hi];
#pragma unroll
    for (int n = 0; n < 4; ++n) bfr[n] = pB[(wc * 64 + n * 16 + lo) * 4 + hi];
#pragma unroll
    for (int m = 0; m < 4; ++m)
#pragma unroll
      for (int n = 0; n < 4; ++n)
        acc[m][n] = __builtin_amdgcn_mfma_f32_16x16x32_bf16(af[m], bfr[n], acc[m][n], 0, 0, 0);
  }
#pragma unroll
  for (int m = 0; m < 4; ++m)
#pragma unroll
    for (int n = 0; n < 4; ++n)
#pragma unroll
      for (int q = 0; q < 4; ++q) {
        const size_t row = row0 + wr * 64 + m * 16 + hi * 4 + q;
        const size_t col = col0 + wc * 64 + n * 16 + lo;
        if ((int)col < N) storeC(&C[row * N + col], acc[m][n][q]);
      }
  if (WRITE_CT && blockIdx.y == 0 && wc == 0) {
    // cols 0..63 are c; emit cT[b][r][t] (packed 4 consecutive t per store)
#pragma unroll
    for (int m = 0; m < 4; ++m)
#pragma unroll
      for (int n = 0; n < 4; ++n) {
        bf16x4 o;
#pragma unroll
        for (int q = 0; q < 4; ++q) o[q] = (bf16_t)acc[m][n][q];
        const size_t row = row0 + wr * 64 + m * 16 + hi * 4;   // + q
        const int bb = (int)(row >> 11);            // row / T_
        const int t0 = (int)(row & (T_ - 1));
        const int r = n * 16 + lo;                  // 0..63
        *reinterpret_cast<bf16x4*>(CT + ((size_t)bb * RK + r) * T_ + t0) = o;
      }
  }
}

// ---------------------------------------------------------------- flash attention, no-max softmax + LDS-staged K/V
// Final: byte-exact r13/r18 loop (best measured attn: 54.3us across 8 variants).
// 128 q-rows/block, 4 waves; grid 512. l via ones-row MFMA; precomputed offsets.
// CQ [BT,576] = [c | q~ (pre-scaled)], cT [B][64][T], U [BT,512]
__global__ __launch_bounds__(256) void attn_kernel(const bf16_t* __restrict__ CQ,
                                                   const bf16_t* __restrict__ CT,
                                                   bf16_t* __restrict__ U) {
  constexpr int KVT = 64;
  constexpr int NT = T_ / KVT;         // 32 tiles
  constexpr int BUFE = KVT * 64;       // 4096 elements per K (or V) buffer
  __shared__ bf16_t Kl[2][KVT][64];  // [buf][kv][d]   8KB per buf
  __shared__ bf16_t Vl[2][64][KVT];  // [buf][d][kv]   8KB per buf
  const int tid = threadIdx.x;
  const int w = tid >> 6, lane = tid & 63;
  const int lq = lane & 31;        // q column owned by this lane
  const int hi = lane >> 5;        // k-half within fragments
  const int b = blockIdx.z;
  const int h = blockIdx.y;
  const size_t qrow = (size_t)b * T_ + blockIdx.x * 128 + w * 32;
  const bf16_t* __restrict__ cq = CQ + (size_t)b * T_ * CQW;
  const bf16_t* __restrict__ ct = CT + (size_t)b * RK * T_;

  // staging geometry: round q in {0,1}; lane covers row (q*32 + w*8 + lane/8),
  // dest chunk lane&7; source chunk pre-swizzled: (lane&7) ^ (lane>>3)
  const int srow = w * 8 + (lane >> 3);        // + q*32
  const int schunk = (lane & 7) ^ (lane >> 3); // source 16B-chunk (swizzled)

  // Q fragments (B-operand): B[k][q], lane holds Q[q=lq][kc*16 + hi*8 + j]
  bf16x8 qf[4];
#pragma unroll
  for (int kc = 0; kc < 4; ++kc)
    qf[kc] = *reinterpret_cast<const bf16x8*>(
        CQ + (qrow + lq) * CQW + RK + h * RK + kc * 16 + hi * 8);

  f32x16 acc0 = {}, acc1 = {}, accl = {};  // O^T rows 0-31/32-63; accl = l via ones-MFMA

  // ones A-fragment for the l-sum MFMA
  bf16x8 onesf;
#pragma unroll
  for (int j = 0; j < 8; ++j) onesf[j] = (bf16_t)1.0f;

  // precomputed LDS element offsets (chunk XOR is sub-independent: (sub*32+lq)&7 == lq&7)
  const bf16_t* const kl = &Kl[0][0][0];
  const bf16_t* const vl = &Vl[0][0][0];
  const int xr = lq & 7;
  int kch[4], vch[2][2];
#pragma unroll
  for (int kc = 0; kc < 4; ++kc) kch[kc] = ((((kc << 1) | hi)) ^ xr) * 8;
#pragma unroll
  for (int sub = 0; sub < 2; ++sub)
#pragma unroll
    for (int kc = 0; kc < 2; ++kc)
      vch[sub][kc] = ((((sub << 2) | (kc << 1) | hi)) ^ xr) * 8;
  const int roff0 = lq * 64, roff1 = (32 + lq) * 64;   // row bases (K: kv row; V: d row)

  // ---- stage tile 0 (4 gload_lds per wave: 2 K rounds + 2 V rounds)
#pragma unroll
  for (int q = 0; q < 2; ++q) {
    async_load16(cq + (size_t)(q * 32 + srow) * CQW + schunk * 8,
                 &Kl[0][q * 32 + w * 8][0]);
    async_load16(ct + (size_t)(q * 32 + srow) * T_ + schunk * 8,
                 &Vl[0][q * 32 + w * 8][0]);
  }

  for (int t = 0; t < NT; ++t) {
    const int cur = t & 1;
    const int cbo = cur * BUFE;          // current-buffer element offset
    if (t + 1 < NT) {
      const int kvn = (t + 1) * KVT;
#pragma unroll
      for (int q = 0; q < 2; ++q) {
        async_load16(cq + (size_t)(kvn + q * 32 + srow) * CQW + schunk * 8,
                     &Kl[cur ^ 1][q * 32 + w * 8][0]);
        async_load16(ct + (size_t)(q * 32 + srow) * T_ + kvn + schunk * 8,
                     &Vl[cur ^ 1][q * 32 + w * 8][0]);
      }
      asm volatile("s_waitcnt vmcnt(4)" ::: "memory");  // tile t's 4 loads done
    } else {
      asm volatile("s_waitcnt vmcnt(0)" ::: "memory");
    }
    __builtin_amdgcn_s_barrier();
    __builtin_amdgcn_sched_barrier(0);

#pragma unroll
    for (int sub = 0; sub < 2; ++sub) {
      // ---- K fragments from LDS (precomputed offsets)
      const int krb = cbo + (sub ? roff1 : roff0);
      bf16x8 kf[4];
#pragma unroll
      for (int kc = 0; kc < 4; ++kc)
        kf[kc] = *reinterpret_cast<const bf16x8*>(kl + krb + kch[kc]);
      // ---- S^T = K * Q^T
      f32x16 s = {};
#pragma unroll
      for (int kc = 0; kc < 4; ++kc)
        s = __builtin_amdgcn_mfma_f32_32x32x16_bf16(kf[kc], qf[kc], s, 0, 0, 0);

      // ---- P = exp2(s) directly (|s| <~ 3; no max tracking needed)
      float p[16];
#pragma unroll
      for (int i = 0; i < 16; ++i) p[i] = __builtin_amdgcn_exp2f(s[i]);

      // ---- pack P to bf16 + redistribute halves (distinct regs -> permlane safe)
      unsigned pw[8];
#pragma unroll
      for (int i = 0; i < 8; ++i)
        asm("v_cvt_pk_bf16_f32 %0, %1, %2" : "=v"(pw[i]) : "v"(p[2 * i]), "v"(p[2 * i + 1]));
      asm("v_permlane32_swap_b32 %0, %1" : "+v"(pw[0]), "+v"(pw[2]));
      asm("v_permlane32_swap_b32 %0, %1" : "+v"(pw[1]), "+v"(pw[3]));
      asm("v_permlane32_swap_b32 %0, %1" : "+v"(pw[4]), "+v"(pw[6]));
      asm("v_permlane32_swap_b32 %0, %1" : "+v"(pw[5]), "+v"(pw[7]));
      union { unsigned u[4]; bf16x8 v; } pb0, pb1;
      pb0.u[0] = pw[0]; pb0.u[1] = pw[1]; pb0.u[2] = pw[2]; pb0.u[3] = pw[3];
      pb1.u[0] = pw[4]; pb1.u[1] = pw[5]; pb1.u[2] = pw[6]; pb1.u[3] = pw[7];

      // ---- V^T fragments from LDS (precomputed offsets)
      bf16x8 vf0[2], vf1[2];
#pragma unroll
      for (int kc = 0; kc < 2; ++kc) {
        vf0[kc] = *reinterpret_cast<const bf16x8*>(vl + cbo + roff0 + vch[sub][kc]);
        vf1[kc] = *reinterpret_cast<const bf16x8*>(vl + cbo + roff1 + vch[sub][kc]);
      }

      // ---- O^T += V^T * P ; l via ones-row MFMA
      acc0 = __builtin_amdgcn_mfma_f32_32x32x16_bf16(vf0[0], pb0.v, acc0, 0, 0, 0);
      acc0 = __builtin_amdgcn_mfma_f32_32x32x16_bf16(vf0[1], pb1.v, acc0, 0, 0, 0);
      acc1 = __builtin_amdgcn_mfma_f32_32x32x16_bf16(vf1[0], pb0.v, acc1, 0, 0, 0);
      acc1 = __builtin_amdgcn_mfma_f32_32x32x16_bf16(vf1[1], pb1.v, acc1, 0, 0, 0);
      accl = __builtin_amdgcn_mfma_f32_32x32x16_bf16(onesf, pb0.v, accl, 0, 0, 0);
      accl = __builtin_amdgcn_mfma_f32_32x32x16_bf16(onesf, pb1.v, accl, 0, 0, 0);
    }

    __builtin_amdgcn_sched_barrier(0);
    __builtin_amdgcn_s_barrier();   // all waves done reading buf before next stage overwrites
  }

  // ---- epilogue: l = accl[0]; normalize and store U
  const float inv = 1.0f / accl[0];
  const size_t ubase = (qrow + lq) * QC + h * RK;
#pragma unroll
  for (int g = 0; g < 4; ++g) {
    bf16x4 o0, o1;
#pragma unroll
    for (int j = 0; j < 4; ++j) {
      o0[j] = (bf16_t)(acc0[g * 4 + j] * inv);
      o1[j] = (bf16_t)(acc1[g * 4 + j] * inv);
    }
    const int d0 = g * 8 + hi * 4;
    *reinterpret_cast<bf16x4*>(U + ubase + d0) = o0;
    *reinterpret_cast<bf16x4*>(U + ubase + 32 + d0) = o1;
  }
}

// ---------------------------------------------------------------- launch
extern "C" void kernel_launch(void* const* d_in, const int* in_sizes, int n_in,
                              void* d_out, int out_size, void* d_ws, size_t ws_size,
                              hipStream_t stream) {
  const float* x   = (const float*)d_in[0];
  const float* Wq  = (const float*)d_in[1];
  const float* Wkd = (const float*)d_in[2];
  const float* Wku = (const float*)d_in[3];
  const float* Wvu = (const float*)d_in[4];
  const float* Wo  = (const float*)d_in[5];
  float* out = (float*)d_out;

  char* ws = (char*)d_ws;
  bf16_t* xb    = (bf16_t*)(ws + 0);          // 8192*1024 bf16 = 16 MiB
  bf16_t* CQb   = (bf16_t*)(ws + 16777216);   // 8192*576         9 MiB
  bf16_t* Ub    = (bf16_t*)(ws + 26214400);   // 8192*512         8 MiB
  bf16_t* Wcat  = (bf16_t*)(ws + 34603008);   // 576*1024         1.125 MiB
  bf16_t* Wfe   = (bf16_t*)(ws + 35782656);   // 1024*512         1 MiB
  bf16_t* cTb   = (bf16_t*)(ws + 36831232);   // 4*64*2048        1 MiB

  // one fused prep: x-cast + Wkd-cast + Wq_eff + W_eff
  prep_kernel<<<1088 + 8192, 256, 0, stream>>>(x, Wkd, Wku, Wq, Wo, Wvu, xb, Wcat, Wfe);

  // [c | q~] = x @ Wcat^T   [8192, 576]; also emits cT (fused transpose)
  gemm_bt<bf16_t, true><<<dim3(BT / 128, 5), 256, 0, stream>>>(xb, Wcat, CQb, cTb, BT, CQW, DM);
  // attention -> U [8192, 512]
  attn_kernel<<<dim3(T_ / 128, NH, B_), 256, 0, stream>>>(CQb, cTb, Ub);
  // out = U @ W_eff^T    [8192, 1024] f32
  gemm_bt<float, false><<<dim3(BT / 128, DM / 128), 256, 0, stream>>>(Ub, Wfe, out, nullptr, BT, DM, QC);
}